// Round 2
// baseline (1553.706 us; speedup 1.0000x reference)
//
#include <hip/hip_runtime.h>
#include <hip/hip_bf16.h>

#define TPB 256

// ---------------- GEMM: C[M,Nc] = A[M,K] @ B[K,Nc] + bias ----------------
#define BM 64
#define BN 64
#define BK 16

template <bool RELU>
__global__ __launch_bounds__(256) void gemm_bias_kernel(
    const float* __restrict__ A, const float* __restrict__ B,
    const float* __restrict__ bias,
    float* __restrict__ C,
    int M, int Nc, int K)
{
    __shared__ float As[BK][BM + 1];
    __shared__ float Bs[BK][BN];

    const int t  = threadIdx.x;
    const int bm = blockIdx.x * BM;
    const int bn = blockIdx.y * BN;
    const int tx = t & 15;       // 0..15 -> 4 cols each
    const int ty = t >> 4;       // 0..15 -> 4 rows each

    float acc[4][4] = {};

    for (int k0 = 0; k0 < K; k0 += BK) {
        // A tile: thread t loads A[bm + t/4][k0 + (t%4)*4 .. +3]
        {
            const int row = bm + (t >> 2);
            const int kk  = (t & 3) * 4;
            float4 v = make_float4(0.f, 0.f, 0.f, 0.f);
            if (row < M)
                v = *reinterpret_cast<const float4*>(A + (size_t)row * K + k0 + kk);
            As[kk + 0][t >> 2] = v.x;
            As[kk + 1][t >> 2] = v.y;
            As[kk + 2][t >> 2] = v.z;
            As[kk + 3][t >> 2] = v.w;
        }
        // B tile: thread t loads B[k0 + t/16][bn + (t%16)*4 .. +3]
        {
            const int kr  = t >> 4;
            const int col = (t & 15) * 4;
            float4 v = *reinterpret_cast<const float4*>(B + (size_t)(k0 + kr) * Nc + bn + col);
            Bs[kr][col + 0] = v.x;
            Bs[kr][col + 1] = v.y;
            Bs[kr][col + 2] = v.z;
            Bs[kr][col + 3] = v.w;
        }
        __syncthreads();

#pragma unroll
        for (int k = 0; k < BK; ++k) {
            float a[4], b[4];
#pragma unroll
            for (int i = 0; i < 4; ++i) a[i] = As[k][ty * 4 + i];
#pragma unroll
            for (int j = 0; j < 4; ++j) b[j] = Bs[k][tx * 4 + j];
#pragma unroll
            for (int i = 0; i < 4; ++i)
#pragma unroll
                for (int j = 0; j < 4; ++j) acc[i][j] += a[i] * b[j];
        }
        __syncthreads();
    }

#pragma unroll
    for (int i = 0; i < 4; ++i) {
        const int row = bm + ty * 4 + i;
        if (row >= M) continue;
#pragma unroll
        for (int j = 0; j < 4; ++j) {
            const int col = bn + tx * 4 + j;
            float v = acc[i][j] + bias[col];
            if (RELU) v = fmaxf(v, 0.f);
            C[(size_t)row * Nc + col] = v;
        }
    }
}

// ---------------- degree count ----------------
__global__ void count_kernel(const int* __restrict__ dst, float* __restrict__ cnt, int E)
{
    int e = blockIdx.x * TPB + threadIdx.x;
    if (e < E) atomicAdd(&cnt[dst[e]], 1.0f);
}

// ---------------- scatter-add of gathered rows ----------------
// agg[dst[e]][d] += xt[src[e]][d], one thread per (edge, feature)
__global__ void scatter_add_kernel(const float* __restrict__ xt,
                                   const int* __restrict__ src,
                                   const int* __restrict__ dst,
                                   float* __restrict__ agg,
                                   long long total, int logF)
{
    long long idx = (long long)blockIdx.x * TPB + threadIdx.x;
    if (idx >= total) return;
    const int e = (int)(idx >> logF);
    const int d = (int)(idx & ((1 << logF) - 1));
    const int s  = src[e];
    const int dd = dst[e];
    const float v = xt[((size_t)s << logF) + d];
    atomicAdd(&agg[((size_t)dd << logF) + d], v);
}

// ---------------- mean + relu + residual (and optional second output) ----------------
template <bool WRITE_Z>
__global__ void finish_kernel(const float* __restrict__ agg,
                              const float* __restrict__ xt,
                              const float* __restrict__ cnt,
                              float* __restrict__ outf,
                              float* __restrict__ zout,
                              long long total, int logF)
{
    long long idx = (long long)blockIdx.x * TPB + threadIdx.x;
    if (idx >= total) return;
    const int n = (int)(idx >> logF);
    const float c = cnt[n];
    const float m = agg[idx] / fmaxf(c, 1.0f);
    const float v = fmaxf(m, 0.0f) + xt[idx];
    outf[idx] = v;
    if (WRITE_Z) zout[idx] = v;
}

extern "C" void kernel_launch(void* const* d_in, const int* in_sizes, int n_in,
                              void* d_out, int out_size, void* d_ws, size_t ws_size,
                              hipStream_t stream)
{
    const int IN_DIM = 256, HID = 256, LAT = 128, DEC_HID = 512;
    const int N = in_sizes[0] / IN_DIM;     // 50000
    const int E = in_sizes[1] / 2;          // 800000

    const float* x   = (const float*)d_in[0];
    const int*   ei  = (const int*)d_in[1];
    const float* W1  = (const float*)d_in[2];
    const float* b1  = (const float*)d_in[3];
    const float* W2  = (const float*)d_in[4];
    const float* b2  = (const float*)d_in[5];
    const float* Wd1 = (const float*)d_in[6];
    const float* bd1 = (const float*)d_in[7];
    const float* Wd2 = (const float*)d_in[8];
    const float* bd2 = (const float*)d_in[9];

    const int* src = ei;
    const int* dst = ei + E;

    // ws arena: bufA/bufB/bufC each N*256 f32, then cnt N f32  (~154 MB)
    float* bufA = (float*)d_ws;
    float* bufB = bufA + (size_t)N * 256;
    float* bufC = bufB + (size_t)N * 256;
    float* cnt  = bufC + (size_t)N * 256;

    float* out_xhat = (float*)d_out;
    float* out_z    = out_xhat + (size_t)N * IN_DIM;

    dim3 blk(TPB);

    // degree counts (shared by both GCN layers)
    hipMemsetAsync(cnt, 0, (size_t)N * 4, stream);
    count_kernel<<<(E + TPB - 1) / TPB, blk, 0, stream>>>(dst, cnt, E);

    // ---- GCN layer 1: xt1 = x@W1+b1 (bufA); agg1 (bufB); h (bufC) ----
    hipMemsetAsync(bufB, 0, (size_t)N * HID * 4, stream);
    {
        dim3 grid((N + BM - 1) / BM, HID / BN);
        gemm_bias_kernel<false><<<grid, blk, 0, stream>>>(x, W1, b1, bufA, N, HID, IN_DIM);
    }
    {
        long long total = (long long)E * HID;
        scatter_add_kernel<<<(unsigned)((total + TPB - 1) / TPB), blk, 0, stream>>>(
            bufA, src, dst, bufB, total, 8);
        long long tn = (long long)N * HID;
        finish_kernel<false><<<(unsigned)((tn + TPB - 1) / TPB), blk, 0, stream>>>(
            bufB, bufA, cnt, bufC, nullptr, tn, 8);
    }

    // ---- GCN layer 2: xt2 = h@W2+b2 (bufA); agg2 (bufB); z (bufC + out_z) ----
    {
        dim3 grid((N + BM - 1) / BM, LAT / BN);
        gemm_bias_kernel<false><<<grid, blk, 0, stream>>>(bufC, W2, b2, bufA, N, LAT, HID);
    }
    hipMemsetAsync(bufB, 0, (size_t)N * LAT * 4, stream);
    {
        long long total = (long long)E * LAT;
        scatter_add_kernel<<<(unsigned)((total + TPB - 1) / TPB), blk, 0, stream>>>(
            bufA, src, dst, bufB, total, 7);
        long long tn = (long long)N * LAT;
        finish_kernel<true><<<(unsigned)((tn + TPB - 1) / TPB), blk, 0, stream>>>(
            bufB, bufA, cnt, bufC, out_z, tn, 7);
    }

    // ---- decoder: hdec = relu(z@Wd1+bd1) into bufA..bufB (102.4 MB contiguous) ----
    {
        dim3 grid((N + BM - 1) / BM, DEC_HID / BN);
        gemm_bias_kernel<true><<<grid, blk, 0, stream>>>(bufC, Wd1, bd1, bufA, N, DEC_HID, LAT);
    }
    // ---- x_hat = hdec@Wd2+bd2 -> f32 d_out ----
    {
        dim3 grid((N + BM - 1) / BM, IN_DIM / BN);
        gemm_bias_kernel<false><<<grid, blk, 0, stream>>>(bufA, Wd2, bd2, out_xhat, N, IN_DIM, DEC_HID);
    }
}

// Round 3
// 844.239 us; speedup vs baseline: 1.8404x; 1.8404x over previous
//
#include <hip/hip_runtime.h>
#include <hip/hip_bf16.h>

#define TPB 256

// ---------------- GEMM: C[M,Nc] = A[M,K] @ B[K,Nc] + bias ----------------
#define BM 64
#define BN 64
#define BK 16

template <bool RELU>
__global__ __launch_bounds__(256) void gemm_bias_kernel(
    const float* __restrict__ A, const float* __restrict__ B,
    const float* __restrict__ bias,
    float* __restrict__ C,
    int M, int Nc, int K)
{
    __shared__ float As[BK][BM + 1];
    __shared__ float Bs[BK][BN];

    const int t  = threadIdx.x;
    const int bm = blockIdx.x * BM;
    const int bn = blockIdx.y * BN;
    const int tx = t & 15;
    const int ty = t >> 4;

    float acc[4][4] = {};

    for (int k0 = 0; k0 < K; k0 += BK) {
        {
            const int row = bm + (t >> 2);
            const int kk  = (t & 3) * 4;
            float4 v = make_float4(0.f, 0.f, 0.f, 0.f);
            if (row < M)
                v = *reinterpret_cast<const float4*>(A + (size_t)row * K + k0 + kk);
            As[kk + 0][t >> 2] = v.x;
            As[kk + 1][t >> 2] = v.y;
            As[kk + 2][t >> 2] = v.z;
            As[kk + 3][t >> 2] = v.w;
        }
        {
            const int kr  = t >> 4;
            const int col = (t & 15) * 4;
            float4 v = *reinterpret_cast<const float4*>(B + (size_t)(k0 + kr) * Nc + bn + col);
            Bs[kr][col + 0] = v.x;
            Bs[kr][col + 1] = v.y;
            Bs[kr][col + 2] = v.z;
            Bs[kr][col + 3] = v.w;
        }
        __syncthreads();

#pragma unroll
        for (int k = 0; k < BK; ++k) {
            float a[4], b[4];
#pragma unroll
            for (int i = 0; i < 4; ++i) a[i] = As[k][ty * 4 + i];
#pragma unroll
            for (int j = 0; j < 4; ++j) b[j] = Bs[k][tx * 4 + j];
#pragma unroll
            for (int i = 0; i < 4; ++i)
#pragma unroll
                for (int j = 0; j < 4; ++j) acc[i][j] += a[i] * b[j];
        }
        __syncthreads();
    }

#pragma unroll
    for (int i = 0; i < 4; ++i) {
        const int row = bm + ty * 4 + i;
        if (row >= M) continue;
#pragma unroll
        for (int j = 0; j < 4; ++j) {
            const int col = bn + tx * 4 + j;
            float v = acc[i][j] + bias[col];
            if (RELU) v = fmaxf(v, 0.f);
            C[(size_t)row * Nc + col] = v;
        }
    }
}

// ---------------- CSR build ----------------
__global__ void hist_kernel(const int* __restrict__ dst, int* __restrict__ counts, int E)
{
    int e = blockIdx.x * TPB + threadIdx.x;
    if (e < E) atomicAdd(&counts[dst[e]], 1);
}

// single-block exclusive scan over counts -> offsets, cursor
__global__ void scan_kernel(const int* __restrict__ counts,
                            int* __restrict__ offsets, int* __restrict__ cursor, int N)
{
    __shared__ int partial[TPB];
    const int t = threadIdx.x;
    const int chunk = (N + TPB - 1) / TPB;
    const int lo = t * chunk;
    const int hi = min(lo + chunk, N);
    int s = 0;
    for (int i = lo; i < hi; ++i) s += counts[i];
    partial[t] = s;
    __syncthreads();
    // Hillis-Steele inclusive scan
    for (int d = 1; d < TPB; d <<= 1) {
        int v = (t >= d) ? partial[t - d] : 0;
        __syncthreads();
        partial[t] += v;
        __syncthreads();
    }
    int base = (t == 0) ? 0 : partial[t - 1];
    for (int i = lo; i < hi; ++i) {
        offsets[i] = base;
        cursor[i]  = base;
        base += counts[i];
    }
}

__global__ void build_perm_kernel(const int* __restrict__ src, const int* __restrict__ dst,
                                  int* __restrict__ cursor, int* __restrict__ perm, int E)
{
    int e = blockIdx.x * TPB + threadIdx.x;
    if (e < E) {
        int pos = atomicAdd(&cursor[dst[e]], 1);
        perm[pos] = src[e];
    }
}

// ---------------- CSR gather aggregation + mean + relu + residual ----------------
// F threads per node (256 threads/block handle 256/F nodes)
template <int F, bool WRITE_Z>
__global__ __launch_bounds__(256) void agg_kernel(
    const float* __restrict__ xt,
    const int* __restrict__ offsets, const int* __restrict__ counts,
    const int* __restrict__ perm,
    float* __restrict__ out, float* __restrict__ zout, int N)
{
    const int node = blockIdx.x * (TPB / F) + threadIdx.x / F;
    const int f    = threadIdx.x % F;
    if (node >= N) return;

    const int start = offsets[node];
    const int deg   = counts[node];

    float acc = 0.f;
    int j = 0;
    for (; j + 4 <= deg; j += 4) {
        const int s0 = perm[start + j + 0];
        const int s1 = perm[start + j + 1];
        const int s2 = perm[start + j + 2];
        const int s3 = perm[start + j + 3];
        acc += xt[(size_t)s0 * F + f];
        acc += xt[(size_t)s1 * F + f];
        acc += xt[(size_t)s2 * F + f];
        acc += xt[(size_t)s3 * F + f];
    }
    for (; j < deg; ++j)
        acc += xt[(size_t)perm[start + j] * F + f];

    const float m = acc / (float)max(deg, 1);
    const float v = fmaxf(m, 0.f) + xt[(size_t)node * F + f];
    out[(size_t)node * F + f] = v;
    if (WRITE_Z) zout[(size_t)node * F + f] = v;
}

extern "C" void kernel_launch(void* const* d_in, const int* in_sizes, int n_in,
                              void* d_out, int out_size, void* d_ws, size_t ws_size,
                              hipStream_t stream)
{
    const int IN_DIM = 256, HID = 256, LAT = 128, DEC_HID = 512;
    const int N = in_sizes[0] / IN_DIM;     // 50000
    const int E = in_sizes[1] / 2;          // 800000

    const float* x   = (const float*)d_in[0];
    const int*   ei  = (const int*)d_in[1];
    const float* W1  = (const float*)d_in[2];
    const float* b1  = (const float*)d_in[3];
    const float* W2  = (const float*)d_in[4];
    const float* b2  = (const float*)d_in[5];
    const float* Wd1 = (const float*)d_in[6];
    const float* bd1 = (const float*)d_in[7];
    const float* Wd2 = (const float*)d_in[8];
    const float* bd2 = (const float*)d_in[9];

    const int* src = ei;
    const int* dst = ei + E;

    // ws arena: bufA/bufB/bufC each N*256 f32 (153.6 MB), then CSR ints (~3.8 MB)
    float* bufA = (float*)d_ws;
    float* bufB = bufA + (size_t)N * 256;
    float* bufC = bufB + (size_t)N * 256;
    int*   counts  = (int*)(bufC + (size_t)N * 256);
    int*   offsets = counts + N;
    int*   cursor  = offsets + N;
    int*   perm    = cursor + N;

    float* out_xhat = (float*)d_out;
    float* out_z    = out_xhat + (size_t)N * IN_DIM;

    dim3 blk(TPB);
    const int egrid = (E + TPB - 1) / TPB;

    // ---- CSR build (shared by both layers) ----
    hipMemsetAsync(counts, 0, (size_t)N * 4, stream);
    hist_kernel<<<egrid, blk, 0, stream>>>(dst, counts, E);
    scan_kernel<<<1, blk, 0, stream>>>(counts, offsets, cursor, N);
    build_perm_kernel<<<egrid, blk, 0, stream>>>(src, dst, cursor, perm, E);

    // ---- GCN layer 1: xt1 = x@W1+b1 (bufA); h = agg (bufC) ----
    {
        dim3 grid((N + BM - 1) / BM, HID / BN);
        gemm_bias_kernel<false><<<grid, blk, 0, stream>>>(x, W1, b1, bufA, N, HID, IN_DIM);
    }
    agg_kernel<256, false><<<N, blk, 0, stream>>>(bufA, offsets, counts, perm, bufC, nullptr, N);

    // ---- GCN layer 2: xt2 = h@W2+b2 (bufA); z = agg -> out_z ----
    {
        dim3 grid((N + BM - 1) / BM, LAT / BN);
        gemm_bias_kernel<false><<<grid, blk, 0, stream>>>(bufC, W2, b2, bufA, N, LAT, HID);
    }
    agg_kernel<128, false><<<(N + 1) / 2, blk, 0, stream>>>(bufA, offsets, counts, perm, out_z, nullptr, N);

    // ---- decoder: hdec = relu(z@Wd1+bd1) into bufB..bufC (contiguous 102.4 MB) ----
    {
        dim3 grid((N + BM - 1) / BM, DEC_HID / BN);
        gemm_bias_kernel<true><<<grid, blk, 0, stream>>>(out_z, Wd1, bd1, bufB, N, DEC_HID, LAT);
    }
    // ---- x_hat = hdec@Wd2+bd2 -> f32 d_out ----
    {
        dim3 grid((N + BM - 1) / BM, IN_DIM / BN);
        gemm_bias_kernel<false><<<grid, blk, 0, stream>>>(bufB, Wd2, bd2, out_xhat, N, IN_DIM, DEC_HID);
    }
}

// Round 4
// 609.000 us; speedup vs baseline: 2.5512x; 1.3863x over previous
//
#include <hip/hip_runtime.h>
#include <hip/hip_bf16.h>

#define TPB 256

typedef __attribute__((ext_vector_type(8))) short short8;
typedef __attribute__((ext_vector_type(4))) float f32x4;

__device__ __forceinline__ unsigned short f2bf(float f) {
    unsigned int u = __float_as_uint(f);
    u = (u + 0x7FFFu + ((u >> 16) & 1u)) >> 16;   // RNE
    return (unsigned short)u;
}

// ---------------- weight transpose + f32->bf16: Wt[Nc][K] ----------------
__global__ void transpose_convert_kernel(const float* __restrict__ W,
                                         unsigned short* __restrict__ Wt,
                                         int K, int Nc)
{
    __shared__ float tile[32][33];
    const int tx = threadIdx.x;   // 0..31
    const int ty = threadIdx.y;   // 0..7
    const int k0 = blockIdx.y * 32;
    const int n0 = blockIdx.x * 32;
#pragma unroll
    for (int i = 0; i < 4; ++i)
        tile[ty + i * 8][tx] = W[(size_t)(k0 + ty + i * 8) * Nc + n0 + tx];
    __syncthreads();
#pragma unroll
    for (int i = 0; i < 4; ++i)
        Wt[(size_t)(n0 + ty + i * 8) * K + k0 + tx] = f2bf(tile[tx][ty + i * 8]);
}

// ---------------- MFMA GEMM: C[M,Nc] = A[M,K](f32) @ Wt^T(bf16) + bias ----------------
// 128x128 tile, BK=64, 4 waves (2x2 of 64x64), 16x16x32 bf16 MFMA.
template <bool RELU>
__global__ __launch_bounds__(256) void mfma_gemm_kernel(
    const float* __restrict__ A, const unsigned short* __restrict__ Bt,
    const float* __restrict__ bias, float* __restrict__ C,
    int M, int Nc, int K)
{
    __shared__ unsigned short lds[2 * 128 * 64];   // A tile then B tile, 32 KB

    const int t  = threadIdx.x;
    const int l  = t & 63;
    const int w  = t >> 6;
    const int wm = w >> 1, wn = w & 1;
    const int bm = blockIdx.x * 128;
    const int bn = blockIdx.y * 128;

    f32x4 acc[4][4] = {};

    const int r  = t >> 1;         // staging row 0..127
    const int kh = (t & 1) * 32;   // k-half (elements)

    for (int k0 = 0; k0 < K; k0 += 64) {
        // ---- stage A (f32 -> bf16, XOR-swizzled) ----
        {
            const int gm = bm + r;
            const float* ap = A + (size_t)gm * K + k0 + kh;
#pragma unroll
            for (int c = 0; c < 4; ++c) {
                short8 v;
                if (gm < M) {
                    float4 f0 = *reinterpret_cast<const float4*>(ap + c * 8);
                    float4 f1 = *reinterpret_cast<const float4*>(ap + c * 8 + 4);
                    v[0] = (short)f2bf(f0.x); v[1] = (short)f2bf(f0.y);
                    v[2] = (short)f2bf(f0.z); v[3] = (short)f2bf(f0.w);
                    v[4] = (short)f2bf(f1.x); v[5] = (short)f2bf(f1.y);
                    v[6] = (short)f2bf(f1.z); v[7] = (short)f2bf(f1.w);
                } else {
                    v = (short8)0;
                }
                const int slot = (((t & 1) * 4 + c) ^ (r & 7));
                *reinterpret_cast<short8*>(&lds[r * 64 + slot * 8]) = v;
            }
        }
        // ---- stage B (bf16 direct, XOR-swizzled) ----
        {
            const unsigned short* bp = Bt + (size_t)(bn + r) * K + k0 + kh;
#pragma unroll
            for (int c = 0; c < 4; ++c) {
                short8 v = *reinterpret_cast<const short8*>(bp + c * 8);
                const int slot = (((t & 1) * 4 + c) ^ (r & 7));
                *reinterpret_cast<short8*>(&lds[8192 + r * 64 + slot * 8]) = v;
            }
        }
        __syncthreads();

#pragma unroll
        for (int kk = 0; kk < 2; ++kk) {
            short8 af[4], bfr[4];
#pragma unroll
            for (int mf = 0; mf < 4; ++mf) {
                const int row  = wm * 64 + mf * 16 + (l & 15);
                const int slot = (kk * 4 + (l >> 4)) ^ (row & 7);
                af[mf] = *reinterpret_cast<const short8*>(&lds[row * 64 + slot * 8]);
            }
#pragma unroll
            for (int nf = 0; nf < 4; ++nf) {
                const int row  = wn * 64 + nf * 16 + (l & 15);
                const int slot = (kk * 4 + (l >> 4)) ^ (row & 7);
                bfr[nf] = *reinterpret_cast<const short8*>(&lds[8192 + row * 64 + slot * 8]);
            }
#pragma unroll
            for (int mf = 0; mf < 4; ++mf)
#pragma unroll
                for (int nf = 0; nf < 4; ++nf)
                    acc[mf][nf] = __builtin_amdgcn_mfma_f32_16x16x32_bf16(
                        af[mf], bfr[nf], acc[mf][nf], 0, 0, 0);
        }
        __syncthreads();
    }

    // ---- epilogue: + bias, optional relu, f32 store ----
#pragma unroll
    for (int nf = 0; nf < 4; ++nf) {
        const int n = bn + wn * 64 + nf * 16 + (l & 15);
        const float bv = bias[n];
#pragma unroll
        for (int mf = 0; mf < 4; ++mf) {
#pragma unroll
            for (int rr = 0; rr < 4; ++rr) {
                const int m = bm + wm * 64 + mf * 16 + (l >> 4) * 4 + rr;
                if (m < M) {
                    float v = acc[mf][nf][rr] + bv;
                    if (RELU) v = fmaxf(v, 0.f);
                    C[(size_t)m * Nc + n] = v;
                }
            }
        }
    }
}

// ---------------- CSR build ----------------
__global__ void hist_kernel(const int* __restrict__ dst, int* __restrict__ counts, int E)
{
    int e = blockIdx.x * TPB + threadIdx.x;
    if (e < E) atomicAdd(&counts[dst[e]], 1);
}

__global__ void scan_kernel(const int* __restrict__ counts,
                            int* __restrict__ offsets, int* __restrict__ cursor, int N)
{
    __shared__ int partial[TPB];
    const int t = threadIdx.x;
    const int chunk = (N + TPB - 1) / TPB;
    const int lo = t * chunk;
    const int hi = min(lo + chunk, N);
    int s = 0;
    for (int i = lo; i < hi; ++i) s += counts[i];
    partial[t] = s;
    __syncthreads();
    for (int d = 1; d < TPB; d <<= 1) {
        int v = (t >= d) ? partial[t - d] : 0;
        __syncthreads();
        partial[t] += v;
        __syncthreads();
    }
    int base = (t == 0) ? 0 : partial[t - 1];
    for (int i = lo; i < hi; ++i) {
        offsets[i] = base;
        cursor[i]  = base;
        base += counts[i];
    }
}

__global__ void build_perm_kernel(const int* __restrict__ src, const int* __restrict__ dst,
                                  int* __restrict__ cursor, int* __restrict__ perm, int E)
{
    int e = blockIdx.x * TPB + threadIdx.x;
    if (e < E) {
        int pos = atomicAdd(&cursor[dst[e]], 1);
        perm[pos] = src[e];
    }
}

// ---------------- CSR gather aggregation + mean + relu + residual ----------------
template <int F, bool WRITE_Z>
__global__ __launch_bounds__(256) void agg_kernel(
    const float* __restrict__ xt,
    const int* __restrict__ offsets, const int* __restrict__ counts,
    const int* __restrict__ perm,
    float* __restrict__ out, float* __restrict__ zout, int N)
{
    const int node = blockIdx.x * (TPB / F) + threadIdx.x / F;
    const int f    = threadIdx.x % F;
    if (node >= N) return;

    const int start = offsets[node];
    const int deg   = counts[node];

    float acc = 0.f;
    int j = 0;
    for (; j + 4 <= deg; j += 4) {
        const int s0 = perm[start + j + 0];
        const int s1 = perm[start + j + 1];
        const int s2 = perm[start + j + 2];
        const int s3 = perm[start + j + 3];
        acc += xt[(size_t)s0 * F + f];
        acc += xt[(size_t)s1 * F + f];
        acc += xt[(size_t)s2 * F + f];
        acc += xt[(size_t)s3 * F + f];
    }
    for (; j < deg; ++j)
        acc += xt[(size_t)perm[start + j] * F + f];

    const float m = acc / (float)max(deg, 1);
    const float v = fmaxf(m, 0.f) + xt[(size_t)node * F + f];
    out[(size_t)node * F + f] = v;
    if (WRITE_Z) zout[(size_t)node * F + f] = v;
}

extern "C" void kernel_launch(void* const* d_in, const int* in_sizes, int n_in,
                              void* d_out, int out_size, void* d_ws, size_t ws_size,
                              hipStream_t stream)
{
    const int IN_DIM = 256, HID = 256, LAT = 128, DEC_HID = 512;
    const int N = in_sizes[0] / IN_DIM;     // 50000
    const int E = in_sizes[1] / 2;          // 800000

    const float* x   = (const float*)d_in[0];
    const int*   ei  = (const int*)d_in[1];
    const float* W1  = (const float*)d_in[2];
    const float* b1  = (const float*)d_in[3];
    const float* W2  = (const float*)d_in[4];
    const float* b2  = (const float*)d_in[5];
    const float* Wd1 = (const float*)d_in[6];
    const float* bd1 = (const float*)d_in[7];
    const float* Wd2 = (const float*)d_in[8];
    const float* bd2 = (const float*)d_in[9];

    const int* src = ei;
    const int* dst = ei + E;

    // ws arena: bufA/bufB/bufC each N*256 f32 (153.6 MB), CSR ints, bf16 weights
    float* bufA = (float*)d_ws;
    float* bufB = bufA + (size_t)N * 256;
    float* bufC = bufB + (size_t)N * 256;
    int*   counts  = (int*)(bufC + (size_t)N * 256);
    int*   offsets = counts + N;
    int*   cursor  = offsets + N;
    int*   perm    = cursor + N;
    unsigned short* wt1  = (unsigned short*)(perm + E);        // [256][256]
    unsigned short* wt2  = wt1 + 256 * 256;                    // [128][256]
    unsigned short* wtd1 = wt2 + 128 * 256;                    // [512][128]
    unsigned short* wtd2 = wtd1 + 512 * 128;                   // [256][512]

    float* out_xhat = (float*)d_out;
    float* out_z    = out_xhat + (size_t)N * IN_DIM;

    dim3 blk(TPB);
    const int egrid = (E + TPB - 1) / TPB;
    const int mblocks = (N + 127) / 128;

    // ---- weight transpose/convert (tiny) ----
    {
        dim3 tb(32, 8);
        transpose_convert_kernel<<<dim3(HID / 32, IN_DIM / 32), tb, 0, stream>>>(W1, wt1, IN_DIM, HID);
        transpose_convert_kernel<<<dim3(LAT / 32, HID / 32),    tb, 0, stream>>>(W2, wt2, HID, LAT);
        transpose_convert_kernel<<<dim3(DEC_HID / 32, LAT / 32),tb, 0, stream>>>(Wd1, wtd1, LAT, DEC_HID);
        transpose_convert_kernel<<<dim3(IN_DIM / 32, DEC_HID / 32), tb, 0, stream>>>(Wd2, wtd2, DEC_HID, IN_DIM);
    }

    // ---- CSR build (shared by both layers) ----
    hipMemsetAsync(counts, 0, (size_t)N * 4, stream);
    hist_kernel<<<egrid, blk, 0, stream>>>(dst, counts, E);
    scan_kernel<<<1, blk, 0, stream>>>(counts, offsets, cursor, N);
    build_perm_kernel<<<egrid, blk, 0, stream>>>(src, dst, cursor, perm, E);

    // ---- GCN layer 1: xt1 = x@W1+b1 (bufA); h = agg (bufC) ----
    mfma_gemm_kernel<false><<<dim3(mblocks, HID / 128), blk, 0, stream>>>(
        x, wt1, b1, bufA, N, HID, IN_DIM);
    agg_kernel<256, false><<<N, blk, 0, stream>>>(bufA, offsets, counts, perm, bufC, nullptr, N);

    // ---- GCN layer 2: xt2 = h@W2+b2 (bufA); z = agg -> out_z ----
    mfma_gemm_kernel<false><<<dim3(mblocks, LAT / 128), blk, 0, stream>>>(
        bufC, wt2, b2, bufA, N, LAT, HID);
    agg_kernel<128, false><<<(N + 1) / 2, blk, 0, stream>>>(bufA, offsets, counts, perm, out_z, nullptr, N);

    // ---- decoder: hdec = relu(z@Wd1+bd1) into bufB..bufC (102.4 MB contiguous) ----
    mfma_gemm_kernel<true><<<dim3(mblocks, DEC_HID / 128), blk, 0, stream>>>(
        out_z, wtd1, bd1, bufB, N, DEC_HID, LAT);

    // ---- x_hat = hdec@Wd2+bd2 -> f32 d_out ----
    mfma_gemm_kernel<false><<<dim3(mblocks, IN_DIM / 128), blk, 0, stream>>>(
        bufB, wtd2, bd2, out_xhat, N, IN_DIM, DEC_HID);
}

// Round 5
// 484.601 us; speedup vs baseline: 3.2062x; 1.2567x over previous
//
#include <hip/hip_runtime.h>
#include <hip/hip_bf16.h>

#define TPB 256

typedef __attribute__((ext_vector_type(8))) short short8;
typedef __attribute__((ext_vector_type(4))) float f32x4;

__device__ __forceinline__ unsigned short f2bf(float f) {
    unsigned int u = __float_as_uint(f);
    u = (u + 0x7FFFu + ((u >> 16) & 1u)) >> 16;   // RNE
    return (unsigned short)u;
}
__device__ __forceinline__ float bflo(unsigned int u) { return __uint_as_float(u << 16); }
__device__ __forceinline__ float bfhi(unsigned int u) { return __uint_as_float(u & 0xFFFF0000u); }

// ---------------- weight transpose + f32->bf16: Wt[Nc][K] ----------------
__global__ void transpose_convert_kernel(const float* __restrict__ W,
                                         unsigned short* __restrict__ Wt,
                                         int K, int Nc)
{
    __shared__ float tile[32][33];
    const int tx = threadIdx.x;   // 0..31
    const int ty = threadIdx.y;   // 0..7
    const int k0 = blockIdx.y * 32;
    const int n0 = blockIdx.x * 32;
#pragma unroll
    for (int i = 0; i < 4; ++i)
        tile[ty + i * 8][tx] = W[(size_t)(k0 + ty + i * 8) * Nc + n0 + tx];
    __syncthreads();
#pragma unroll
    for (int i = 0; i < 4; ++i)
        Wt[(size_t)(n0 + ty + i * 8) * K + k0 + tx] = f2bf(tile[tx][ty + i * 8]);
}

// ---------------- A-fragment loaders (f32 converts, bf16 copies) ----------------
__device__ __forceinline__ short8 load_a8(const float* p) {
    float4 f0 = *reinterpret_cast<const float4*>(p);
    float4 f1 = *reinterpret_cast<const float4*>(p + 4);
    short8 v;
    v[0] = (short)f2bf(f0.x); v[1] = (short)f2bf(f0.y);
    v[2] = (short)f2bf(f0.z); v[3] = (short)f2bf(f0.w);
    v[4] = (short)f2bf(f1.x); v[5] = (short)f2bf(f1.y);
    v[6] = (short)f2bf(f1.z); v[7] = (short)f2bf(f1.w);
    return v;
}
__device__ __forceinline__ short8 load_a8(const unsigned short* p) {
    return *reinterpret_cast<const short8*>(p);
}
__device__ __forceinline__ void storeC(float* C, size_t idx, float v)          { C[idx] = v; }
__device__ __forceinline__ void storeC(unsigned short* C, size_t idx, float v) { C[idx] = f2bf(v); }

// ---------------- MFMA GEMM: C[M,Nc] = A[M,K] @ Wt^T(bf16) + bias ----------------
// 128x128 tile, BK=64, 4 waves (2x2 of 64x64), 16x16x32 bf16 MFMA.
template <typename TA, typename TC, bool RELU>
__global__ __launch_bounds__(256) void mfma_gemm_kernel(
    const TA* __restrict__ A, const unsigned short* __restrict__ Bt,
    const float* __restrict__ bias, TC* __restrict__ C,
    int M, int Nc, int K)
{
    __shared__ unsigned short lds[2 * 128 * 64];   // A tile then B tile, 32 KB

    const int t  = threadIdx.x;
    const int l  = t & 63;
    const int w  = t >> 6;
    const int wm = w >> 1, wn = w & 1;
    const int bm = blockIdx.x * 128;
    const int bn = blockIdx.y * 128;

    f32x4 acc[4][4] = {};

    const int r  = t >> 1;         // staging row 0..127
    const int kh = (t & 1) * 32;   // k-half (elements)

    for (int k0 = 0; k0 < K; k0 += 64) {
        // ---- stage A (XOR-swizzled) ----
        {
            const int gm = bm + r;
            const TA* ap = A + (size_t)gm * K + k0 + kh;
#pragma unroll
            for (int c = 0; c < 4; ++c) {
                short8 v = (gm < M) ? load_a8(ap + c * 8) : (short8)0;
                const int slot = (((t & 1) * 4 + c) ^ (r & 7));
                *reinterpret_cast<short8*>(&lds[r * 64 + slot * 8]) = v;
            }
        }
        // ---- stage B (bf16 direct, XOR-swizzled) ----
        {
            const unsigned short* bp = Bt + (size_t)(bn + r) * K + k0 + kh;
#pragma unroll
            for (int c = 0; c < 4; ++c) {
                short8 v = *reinterpret_cast<const short8*>(bp + c * 8);
                const int slot = (((t & 1) * 4 + c) ^ (r & 7));
                *reinterpret_cast<short8*>(&lds[8192 + r * 64 + slot * 8]) = v;
            }
        }
        __syncthreads();

#pragma unroll
        for (int kk = 0; kk < 2; ++kk) {
            short8 af[4], bfr[4];
#pragma unroll
            for (int mf = 0; mf < 4; ++mf) {
                const int row  = wm * 64 + mf * 16 + (l & 15);
                const int slot = (kk * 4 + (l >> 4)) ^ (row & 7);
                af[mf] = *reinterpret_cast<const short8*>(&lds[row * 64 + slot * 8]);
            }
#pragma unroll
            for (int nf = 0; nf < 4; ++nf) {
                const int row  = wn * 64 + nf * 16 + (l & 15);
                const int slot = (kk * 4 + (l >> 4)) ^ (row & 7);
                bfr[nf] = *reinterpret_cast<const short8*>(&lds[8192 + row * 64 + slot * 8]);
            }
#pragma unroll
            for (int mf = 0; mf < 4; ++mf)
#pragma unroll
                for (int nf = 0; nf < 4; ++nf)
                    acc[mf][nf] = __builtin_amdgcn_mfma_f32_16x16x32_bf16(
                        af[mf], bfr[nf], acc[mf][nf], 0, 0, 0);
        }
        __syncthreads();
    }

    // ---- epilogue: + bias, optional relu ----
#pragma unroll
    for (int nf = 0; nf < 4; ++nf) {
        const int n = bn + wn * 64 + nf * 16 + (l & 15);
        const float bv = bias[n];
#pragma unroll
        for (int mf = 0; mf < 4; ++mf) {
#pragma unroll
            for (int rr = 0; rr < 4; ++rr) {
                const int m = bm + wm * 64 + mf * 16 + (l >> 4) * 4 + rr;
                if (m < M) {
                    float v = acc[mf][nf][rr] + bv;
                    if (RELU) v = fmaxf(v, 0.f);
                    storeC(C, (size_t)m * Nc + n, v);
                }
            }
        }
    }
}

// ---------------- CSR build ----------------
__global__ void hist_kernel(const int* __restrict__ dst, int* __restrict__ counts, int E)
{
    int e = blockIdx.x * TPB + threadIdx.x;
    if (e < E) atomicAdd(&counts[dst[e]], 1);
}

__global__ void scan_kernel(const int* __restrict__ counts,
                            int* __restrict__ offsets, int* __restrict__ cursor, int N)
{
    __shared__ int partial[TPB];
    const int t = threadIdx.x;
    const int chunk = (N + TPB - 1) / TPB;
    const int lo = t * chunk;
    const int hi = min(lo + chunk, N);
    int s = 0;
    for (int i = lo; i < hi; ++i) s += counts[i];
    partial[t] = s;
    __syncthreads();
    for (int d = 1; d < TPB; d <<= 1) {
        int v = (t >= d) ? partial[t - d] : 0;
        __syncthreads();
        partial[t] += v;
        __syncthreads();
    }
    int base = (t == 0) ? 0 : partial[t - 1];
    for (int i = lo; i < hi; ++i) {
        offsets[i] = base;
        cursor[i]  = base;
        base += counts[i];
    }
}

__global__ void build_perm_kernel(const int* __restrict__ src, const int* __restrict__ dst,
                                  int* __restrict__ cursor, int* __restrict__ perm, int E)
{
    int e = blockIdx.x * TPB + threadIdx.x;
    if (e < E) {
        int pos = atomicAdd(&cursor[dst[e]], 1);
        perm[pos] = src[e];
    }
}

// ---------------- CSR gather aggregation (bf16) + mean + relu + residual ----------------
// F = features per node (bf16); F/2 uint lanes per node.
template <int F, bool WRITE_ZF32>
__global__ __launch_bounds__(256) void agg_kernel(
    const unsigned int* __restrict__ xt,     // bf16 pairs
    const int* __restrict__ offsets, const int* __restrict__ counts,
    const int* __restrict__ perm,
    unsigned int* __restrict__ out,          // bf16 pairs
    float* __restrict__ zf32,                // optional f32 output (row-major [N][F])
    int N)
{
    constexpr int FH = F / 2;
    const int node = blockIdx.x * (TPB / FH) + threadIdx.x / FH;
    const int f    = threadIdx.x & (FH - 1);
    if (node >= N) return;

    const int start = offsets[node];
    const int deg   = counts[node];

    float a0 = 0.f, a1 = 0.f;
    int j = 0;
    for (; j + 4 <= deg; j += 4) {
        const int s0 = perm[start + j + 0];
        const int s1 = perm[start + j + 1];
        const int s2 = perm[start + j + 2];
        const int s3 = perm[start + j + 3];
        const unsigned int v0 = xt[(size_t)s0 * FH + f];
        const unsigned int v1 = xt[(size_t)s1 * FH + f];
        const unsigned int v2 = xt[(size_t)s2 * FH + f];
        const unsigned int v3 = xt[(size_t)s3 * FH + f];
        a0 += bflo(v0) + bflo(v1) + bflo(v2) + bflo(v3);
        a1 += bfhi(v0) + bfhi(v1) + bfhi(v2) + bfhi(v3);
    }
    for (; j < deg; ++j) {
        const unsigned int v = xt[(size_t)perm[start + j] * FH + f];
        a0 += bflo(v);
        a1 += bfhi(v);
    }

    const float c = (float)max(deg, 1);
    const unsigned int xv = xt[(size_t)node * FH + f];
    const float r0 = fmaxf(a0 / c, 0.f) + bflo(xv);
    const float r1 = fmaxf(a1 / c, 0.f) + bfhi(xv);

    out[(size_t)node * FH + f] = (unsigned int)f2bf(r0) | ((unsigned int)f2bf(r1) << 16);
    if (WRITE_ZF32) {
        float2 z2 = make_float2(r0, r1);
        *reinterpret_cast<float2*>(&zf32[(size_t)node * F + 2 * f]) = z2;
    }
}

extern "C" void kernel_launch(void* const* d_in, const int* in_sizes, int n_in,
                              void* d_out, int out_size, void* d_ws, size_t ws_size,
                              hipStream_t stream)
{
    const int IN_DIM = 256, HID = 256, LAT = 128, DEC_HID = 512;
    const int N = in_sizes[0] / IN_DIM;     // 50000
    const int E = in_sizes[1] / 2;          // 800000

    const float* x   = (const float*)d_in[0];
    const int*   ei  = (const int*)d_in[1];
    const float* W1  = (const float*)d_in[2];
    const float* b1  = (const float*)d_in[3];
    const float* W2  = (const float*)d_in[4];
    const float* b2  = (const float*)d_in[5];
    const float* Wd1 = (const float*)d_in[6];
    const float* bd1 = (const float*)d_in[7];
    const float* Wd2 = (const float*)d_in[8];
    const float* bd2 = (const float*)d_in[9];

    const int* src = ei;
    const int* dst = ei + E;

    // ws arena: bf16 node features (128 MB) + bf16 weights + CSR ints
    unsigned short* xt1  = (unsigned short*)d_ws;             // [N][256]
    unsigned short* h    = xt1  + (size_t)N * 256;            // [N][256]
    unsigned short* xt2  = h    + (size_t)N * 256;            // [N][128]
    unsigned short* zbf  = xt2  + (size_t)N * 128;            // [N][128]
    unsigned short* hdec = zbf  + (size_t)N * 128;            // [N][512]
    unsigned short* wt1  = hdec + (size_t)N * 512;            // [256][256]
    unsigned short* wt2  = wt1  + 256 * 256;                  // [128][256]
    unsigned short* wtd1 = wt2  + 128 * 256;                  // [512][128]
    unsigned short* wtd2 = wtd1 + 512 * 128;                  // [256][512]
    int* counts  = (int*)(wtd2 + 256 * 512);
    int* offsets = counts + N;
    int* cursor  = offsets + N;
    int* perm    = cursor + N;

    float* out_xhat = (float*)d_out;
    float* out_z    = out_xhat + (size_t)N * IN_DIM;

    dim3 blk(TPB);
    const int egrid = (E + TPB - 1) / TPB;
    const int mblocks = (N + 127) / 128;

    // ---- weight transpose/convert (tiny) ----
    {
        dim3 tb(32, 8);
        transpose_convert_kernel<<<dim3(HID / 32, IN_DIM / 32), tb, 0, stream>>>(W1, wt1, IN_DIM, HID);
        transpose_convert_kernel<<<dim3(LAT / 32, HID / 32),    tb, 0, stream>>>(W2, wt2, HID, LAT);
        transpose_convert_kernel<<<dim3(DEC_HID / 32, LAT / 32),tb, 0, stream>>>(Wd1, wtd1, LAT, DEC_HID);
        transpose_convert_kernel<<<dim3(IN_DIM / 32, DEC_HID / 32), tb, 0, stream>>>(Wd2, wtd2, DEC_HID, IN_DIM);
    }

    // ---- CSR build (shared by both layers) ----
    hipMemsetAsync(counts, 0, (size_t)N * 4, stream);
    hist_kernel<<<egrid, blk, 0, stream>>>(dst, counts, E);
    scan_kernel<<<1, blk, 0, stream>>>(counts, offsets, cursor, N);
    build_perm_kernel<<<egrid, blk, 0, stream>>>(src, dst, cursor, perm, E);

    // ---- GCN layer 1: xt1 = x@W1+b1 (bf16); h = agg(xt1) (bf16) ----
    mfma_gemm_kernel<float, unsigned short, false><<<dim3(mblocks, HID / 128), blk, 0, stream>>>(
        x, wt1, b1, xt1, N, HID, IN_DIM);
    agg_kernel<256, false><<<(N + 1) / 2, blk, 0, stream>>>(
        (const unsigned int*)xt1, offsets, counts, perm, (unsigned int*)h, nullptr, N);

    // ---- GCN layer 2: xt2 = h@W2+b2 (bf16); z = agg(xt2) -> out_z f32 + zbf ----
    mfma_gemm_kernel<unsigned short, unsigned short, false><<<dim3(mblocks, LAT / 128), blk, 0, stream>>>(
        h, wt2, b2, xt2, N, LAT, HID);
    agg_kernel<128, true><<<(N + 3) / 4, blk, 0, stream>>>(
        (const unsigned int*)xt2, offsets, counts, perm, (unsigned int*)zbf, out_z, N);

    // ---- decoder: hdec = relu(z@Wd1+bd1) (bf16) ----
    mfma_gemm_kernel<unsigned short, unsigned short, true><<<dim3(mblocks, DEC_HID / 128), blk, 0, stream>>>(
        zbf, wtd1, bd1, hdec, N, DEC_HID, LAT);

    // ---- x_hat = hdec@Wd2+bd2 -> f32 d_out ----
    mfma_gemm_kernel<unsigned short, float, false><<<dim3(mblocks, IN_DIM / 128), blk, 0, stream>>>(
        hdec, wtd2, bd2, out_xhat, N, IN_DIM, DEC_HID);
}

// Round 6
// 383.579 us; speedup vs baseline: 4.0506x; 1.2634x over previous
//
#include <hip/hip_runtime.h>
#include <hip/hip_bf16.h>

#define TPB 256

typedef __attribute__((ext_vector_type(8))) short short8;
typedef __attribute__((ext_vector_type(4))) float f32x4;

__device__ __forceinline__ unsigned short f2bf(float f) {
    unsigned int u = __float_as_uint(f);
    u = (u + 0x7FFFu + ((u >> 16) & 1u)) >> 16;   // RNE
    return (unsigned short)u;
}
__device__ __forceinline__ float bflo(unsigned int u) { return __uint_as_float(u << 16); }
__device__ __forceinline__ float bfhi(unsigned int u) { return __uint_as_float(u & 0xFFFF0000u); }

// ---------------- weight transpose + f32->bf16: Wt[Nc][K] ----------------
__global__ void transpose_convert_kernel(const float* __restrict__ W,
                                         unsigned short* __restrict__ Wt,
                                         int K, int Nc)
{
    __shared__ float tile[32][33];
    const int tx = threadIdx.x;   // 0..31
    const int ty = threadIdx.y;   // 0..7
    const int k0 = blockIdx.y * 32;
    const int n0 = blockIdx.x * 32;
#pragma unroll
    for (int i = 0; i < 4; ++i)
        tile[ty + i * 8][tx] = W[(size_t)(k0 + ty + i * 8) * Nc + n0 + tx];
    __syncthreads();
#pragma unroll
    for (int i = 0; i < 4; ++i)
        Wt[(size_t)(n0 + ty + i * 8) * K + k0 + tx] = f2bf(tile[tx][ty + i * 8]);
}

// ---------------- A-fragment loaders (f32 converts, bf16 copies) ----------------
__device__ __forceinline__ short8 load_a8(const float* p) {
    float4 f0 = *reinterpret_cast<const float4*>(p);
    float4 f1 = *reinterpret_cast<const float4*>(p + 4);
    short8 v;
    v[0] = (short)f2bf(f0.x); v[1] = (short)f2bf(f0.y);
    v[2] = (short)f2bf(f0.z); v[3] = (short)f2bf(f0.w);
    v[4] = (short)f2bf(f1.x); v[5] = (short)f2bf(f1.y);
    v[6] = (short)f2bf(f1.z); v[7] = (short)f2bf(f1.w);
    return v;
}
__device__ __forceinline__ short8 load_a8(const unsigned short* p) {
    return *reinterpret_cast<const short8*>(p);
}
__device__ __forceinline__ void storeC(float* C, size_t idx, float v)          { C[idx] = v; }
__device__ __forceinline__ void storeC(unsigned short* C, size_t idx, float v) { C[idx] = f2bf(v); }

// ---------------- MFMA GEMM: C[M,Nc] = A[M,K] @ Wt^T(bf16) + bias ----------------
// 128x128 tile, BK=64, 4 waves (2x2 of 64x64), 16x16x32 bf16 MFMA.
template <typename TA, typename TC, bool RELU>
__global__ __launch_bounds__(256) void mfma_gemm_kernel(
    const TA* __restrict__ A, const unsigned short* __restrict__ Bt,
    const float* __restrict__ bias, TC* __restrict__ C,
    int M, int Nc, int K)
{
    __shared__ unsigned short lds[2 * 128 * 64];   // A tile then B tile, 32 KB

    const int t  = threadIdx.x;
    const int l  = t & 63;
    const int w  = t >> 6;
    const int wm = w >> 1, wn = w & 1;
    const int bm = blockIdx.x * 128;
    const int bn = blockIdx.y * 128;

    f32x4 acc[4][4] = {};

    const int r  = t >> 1;         // staging row 0..127
    const int kh = (t & 1) * 32;   // k-half (elements)

    for (int k0 = 0; k0 < K; k0 += 64) {
        // ---- stage A (XOR-swizzled) ----
        {
            const int gm = bm + r;
            const TA* ap = A + (size_t)gm * K + k0 + kh;
#pragma unroll
            for (int c = 0; c < 4; ++c) {
                short8 v = (gm < M) ? load_a8(ap + c * 8) : (short8)0;
                const int slot = (((t & 1) * 4 + c) ^ (r & 7));
                *reinterpret_cast<short8*>(&lds[r * 64 + slot * 8]) = v;
            }
        }
        // ---- stage B (bf16 direct, XOR-swizzled) ----
        {
            const unsigned short* bp = Bt + (size_t)(bn + r) * K + k0 + kh;
#pragma unroll
            for (int c = 0; c < 4; ++c) {
                short8 v = *reinterpret_cast<const short8*>(bp + c * 8);
                const int slot = (((t & 1) * 4 + c) ^ (r & 7));
                *reinterpret_cast<short8*>(&lds[8192 + r * 64 + slot * 8]) = v;
            }
        }
        __syncthreads();

#pragma unroll
        for (int kk = 0; kk < 2; ++kk) {
            short8 af[4], bfr[4];
#pragma unroll
            for (int mf = 0; mf < 4; ++mf) {
                const int row  = wm * 64 + mf * 16 + (l & 15);
                const int slot = (kk * 4 + (l >> 4)) ^ (row & 7);
                af[mf] = *reinterpret_cast<const short8*>(&lds[row * 64 + slot * 8]);
            }
#pragma unroll
            for (int nf = 0; nf < 4; ++nf) {
                const int row  = wn * 64 + nf * 16 + (l & 15);
                const int slot = (kk * 4 + (l >> 4)) ^ (row & 7);
                bfr[nf] = *reinterpret_cast<const short8*>(&lds[8192 + row * 64 + slot * 8]);
            }
#pragma unroll
            for (int mf = 0; mf < 4; ++mf)
#pragma unroll
                for (int nf = 0; nf < 4; ++nf)
                    acc[mf][nf] = __builtin_amdgcn_mfma_f32_16x16x32_bf16(
                        af[mf], bfr[nf], acc[mf][nf], 0, 0, 0);
        }
        __syncthreads();
    }

    // ---- epilogue: + bias, optional relu ----
#pragma unroll
    for (int nf = 0; nf < 4; ++nf) {
        const int n = bn + wn * 64 + nf * 16 + (l & 15);
        const float bv = bias[n];
#pragma unroll
        for (int mf = 0; mf < 4; ++mf) {
#pragma unroll
            for (int rr = 0; rr < 4; ++rr) {
                const int m = bm + wm * 64 + mf * 16 + (l >> 4) * 4 + rr;
                if (m < M) {
                    float v = acc[mf][nf][rr] + bv;
                    if (RELU) v = fmaxf(v, 0.f);
                    storeC(C, (size_t)m * Nc + n, v);
                }
            }
        }
    }
}

// ---------------- CSR build ----------------
__global__ void hist_kernel(const int* __restrict__ dst, int* __restrict__ counts, int E)
{
    int e = blockIdx.x * TPB + threadIdx.x;
    if (e < E) atomicAdd(&counts[dst[e]], 1);
}

// ---- 3-phase device-wide exclusive scan (1024 elements per block) ----
__global__ void scan1_kernel(const int* __restrict__ counts,
                             int* __restrict__ local, int* __restrict__ bsum, int N)
{
    __shared__ int sh[TPB];
    const int t = threadIdx.x;
    const int base = blockIdx.x * 1024 + t * 4;
    int v[4];
#pragma unroll
    for (int i = 0; i < 4; ++i) v[i] = (base + i < N) ? counts[base + i] : 0;
    const int s = v[0] + v[1] + v[2] + v[3];
    sh[t] = s;
    __syncthreads();
    for (int d = 1; d < TPB; d <<= 1) {
        int x = (t >= d) ? sh[t - d] : 0;
        __syncthreads();
        sh[t] += x;
        __syncthreads();
    }
    int run = sh[t] - s;   // exclusive prefix within block
#pragma unroll
    for (int i = 0; i < 4; ++i) {
        if (base + i < N) local[base + i] = run;
        run += v[i];
    }
    if (t == TPB - 1) bsum[blockIdx.x] = sh[TPB - 1];
}

__global__ void scan2_kernel(int* __restrict__ bsum, int nb)
{
    __shared__ int sh[TPB];
    const int t = threadIdx.x;
    const int v = (t < nb) ? bsum[t] : 0;
    sh[t] = v;
    __syncthreads();
    for (int d = 1; d < TPB; d <<= 1) {
        int x = (t >= d) ? sh[t - d] : 0;
        __syncthreads();
        sh[t] += x;
        __syncthreads();
    }
    if (t < nb) bsum[t] = sh[t] - v;   // exclusive block base
}

__global__ void scan3_kernel(int* __restrict__ offsets, int* __restrict__ cursor,
                             const int* __restrict__ bsum, int N)
{
    const int i = blockIdx.x * TPB + threadIdx.x;
    if (i < N) {
        const int o = offsets[i] + bsum[i >> 10];
        offsets[i] = o;
        cursor[i]  = o;
    }
}

__global__ void build_perm_kernel(const int* __restrict__ src, const int* __restrict__ dst,
                                  int* __restrict__ cursor, int* __restrict__ perm, int E)
{
    int e = blockIdx.x * TPB + threadIdx.x;
    if (e < E) {
        int pos = atomicAdd(&cursor[dst[e]], 1);
        perm[pos] = src[e];
    }
}

// ---------------- CSR gather aggregation (bf16) + mean + relu + residual ----------------
// F = features per node (bf16); F/2 uint lanes per node.
template <int F, bool WRITE_ZF32>
__global__ __launch_bounds__(256) void agg_kernel(
    const unsigned int* __restrict__ xt,     // bf16 pairs
    const int* __restrict__ offsets, const int* __restrict__ counts,
    const int* __restrict__ perm,
    unsigned int* __restrict__ out,          // bf16 pairs
    float* __restrict__ zf32,                // optional f32 output (row-major [N][F])
    int N)
{
    constexpr int FH = F / 2;
    const int node = blockIdx.x * (TPB / FH) + threadIdx.x / FH;
    const int f    = threadIdx.x & (FH - 1);
    if (node >= N) return;

    const int start = offsets[node];
    const int deg   = counts[node];

    float a0 = 0.f, a1 = 0.f;
    int j = 0;
    for (; j + 4 <= deg; j += 4) {
        const int s0 = perm[start + j + 0];
        const int s1 = perm[start + j + 1];
        const int s2 = perm[start + j + 2];
        const int s3 = perm[start + j + 3];
        const unsigned int v0 = xt[(size_t)s0 * FH + f];
        const unsigned int v1 = xt[(size_t)s1 * FH + f];
        const unsigned int v2 = xt[(size_t)s2 * FH + f];
        const unsigned int v3 = xt[(size_t)s3 * FH + f];
        a0 += bflo(v0) + bflo(v1) + bflo(v2) + bflo(v3);
        a1 += bfhi(v0) + bfhi(v1) + bfhi(v2) + bfhi(v3);
    }
    for (; j < deg; ++j) {
        const unsigned int v = xt[(size_t)perm[start + j] * FH + f];
        a0 += bflo(v);
        a1 += bfhi(v);
    }

    const float c = (float)max(deg, 1);
    const unsigned int xv = xt[(size_t)node * FH + f];
    const float r0 = fmaxf(a0 / c, 0.f) + bflo(xv);
    const float r1 = fmaxf(a1 / c, 0.f) + bfhi(xv);

    out[(size_t)node * FH + f] = (unsigned int)f2bf(r0) | ((unsigned int)f2bf(r1) << 16);
    if (WRITE_ZF32) {
        float2 z2 = make_float2(r0, r1);
        *reinterpret_cast<float2*>(&zf32[(size_t)node * F + 2 * f]) = z2;
    }
}

extern "C" void kernel_launch(void* const* d_in, const int* in_sizes, int n_in,
                              void* d_out, int out_size, void* d_ws, size_t ws_size,
                              hipStream_t stream)
{
    const int IN_DIM = 256, HID = 256, LAT = 128, DEC_HID = 512;
    const int N = in_sizes[0] / IN_DIM;     // 50000
    const int E = in_sizes[1] / 2;          // 800000

    const float* x   = (const float*)d_in[0];
    const int*   ei  = (const int*)d_in[1];
    const float* W1  = (const float*)d_in[2];
    const float* b1  = (const float*)d_in[3];
    const float* W2  = (const float*)d_in[4];
    const float* b2  = (const float*)d_in[5];
    const float* Wd1 = (const float*)d_in[6];
    const float* bd1 = (const float*)d_in[7];
    const float* Wd2 = (const float*)d_in[8];
    const float* bd2 = (const float*)d_in[9];

    const int* src = ei;
    const int* dst = ei + E;

    // ws arena: bf16 node features (128 MB) + bf16 weights + CSR ints
    unsigned short* xt1  = (unsigned short*)d_ws;             // [N][256]
    unsigned short* h    = xt1  + (size_t)N * 256;            // [N][256]
    unsigned short* xt2  = h    + (size_t)N * 256;            // [N][128]
    unsigned short* zbf  = xt2  + (size_t)N * 128;            // [N][128]
    unsigned short* hdec = zbf  + (size_t)N * 128;            // [N][512]
    unsigned short* wt1  = hdec + (size_t)N * 512;            // [256][256]
    unsigned short* wt2  = wt1  + 256 * 256;                  // [128][256]
    unsigned short* wtd1 = wt2  + 128 * 256;                  // [512][128]
    unsigned short* wtd2 = wtd1 + 512 * 128;                  // [256][512]
    int* counts  = (int*)(wtd2 + 256 * 512);
    int* offsets = counts + N;
    int* cursor  = offsets + N;
    int* bsum    = cursor + N;                                 // scan block sums (<=256)
    int* perm    = bsum + 256;

    float* out_xhat = (float*)d_out;
    float* out_z    = out_xhat + (size_t)N * IN_DIM;

    dim3 blk(TPB);
    const int egrid = (E + TPB - 1) / TPB;
    const int mblocks = (N + 127) / 128;
    const int nscan = (N + 1023) / 1024;

    // ---- weight transpose/convert (tiny) ----
    {
        dim3 tb(32, 8);
        transpose_convert_kernel<<<dim3(HID / 32, IN_DIM / 32), tb, 0, stream>>>(W1, wt1, IN_DIM, HID);
        transpose_convert_kernel<<<dim3(LAT / 32, HID / 32),    tb, 0, stream>>>(W2, wt2, HID, LAT);
        transpose_convert_kernel<<<dim3(DEC_HID / 32, LAT / 32),tb, 0, stream>>>(Wd1, wtd1, LAT, DEC_HID);
        transpose_convert_kernel<<<dim3(IN_DIM / 32, DEC_HID / 32), tb, 0, stream>>>(Wd2, wtd2, DEC_HID, IN_DIM);
    }

    // ---- CSR build (shared by both layers) ----
    hipMemsetAsync(counts, 0, (size_t)N * 4, stream);
    hist_kernel<<<egrid, blk, 0, stream>>>(dst, counts, E);
    scan1_kernel<<<nscan, blk, 0, stream>>>(counts, offsets, bsum, N);
    scan2_kernel<<<1, blk, 0, stream>>>(bsum, nscan);
    scan3_kernel<<<(N + TPB - 1) / TPB, blk, 0, stream>>>(offsets, cursor, bsum, N);
    build_perm_kernel<<<egrid, blk, 0, stream>>>(src, dst, cursor, perm, E);

    // ---- GCN layer 1: xt1 = x@W1+b1 (bf16); h = agg(xt1) (bf16) ----
    mfma_gemm_kernel<float, unsigned short, false><<<dim3(mblocks, HID / 128), blk, 0, stream>>>(
        x, wt1, b1, xt1, N, HID, IN_DIM);
    agg_kernel<256, false><<<(N + 1) / 2, blk, 0, stream>>>(
        (const unsigned int*)xt1, offsets, counts, perm, (unsigned int*)h, nullptr, N);

    // ---- GCN layer 2: xt2 = h@W2+b2 (bf16); z = agg(xt2) -> out_z f32 + zbf ----
    mfma_gemm_kernel<unsigned short, unsigned short, false><<<dim3(mblocks, LAT / 128), blk, 0, stream>>>(
        h, wt2, b2, xt2, N, LAT, HID);
    agg_kernel<128, true><<<(N + 3) / 4, blk, 0, stream>>>(
        (const unsigned int*)xt2, offsets, counts, perm, (unsigned int*)zbf, out_z, N);

    // ---- decoder: hdec = relu(z@Wd1+bd1) (bf16) ----
    mfma_gemm_kernel<unsigned short, unsigned short, true><<<dim3(mblocks, DEC_HID / 128), blk, 0, stream>>>(
        zbf, wtd1, bd1, hdec, N, DEC_HID, LAT);

    // ---- x_hat = hdec@Wd2+bd2 -> f32 d_out ----
    mfma_gemm_kernel<unsigned short, float, false><<<dim3(mblocks, IN_DIM / 128), blk, 0, stream>>>(
        hdec, wtd2, bd2, out_xhat, N, IN_DIM, DEC_HID);
}

// Round 7
// 344.479 us; speedup vs baseline: 4.5103x; 1.1135x over previous
//
#include <hip/hip_runtime.h>
#include <hip/hip_bf16.h>

#define TPB 256

typedef __attribute__((ext_vector_type(8))) short short8;
typedef __attribute__((ext_vector_type(4))) float f32x4;

__device__ __forceinline__ unsigned short f2bf(float f) {
    unsigned int u = __float_as_uint(f);
    u = (u + 0x7FFFu + ((u >> 16) & 1u)) >> 16;   // RNE
    return (unsigned short)u;
}
__device__ __forceinline__ float bflo(unsigned int u) { return __uint_as_float(u << 16); }
__device__ __forceinline__ float bfhi(unsigned int u) { return __uint_as_float(u & 0xFFFF0000u); }

// ---------------- fused weight transpose + f32->bf16 for all 4 weights ----------------
__global__ void transpose_convert_all(
    const float* __restrict__ Wa, unsigned short* __restrict__ Ta, int Ka, int Na,
    const float* __restrict__ Wb, unsigned short* __restrict__ Tb, int Kb, int Nb,
    const float* __restrict__ Wc, unsigned short* __restrict__ Tc, int Kc, int Nc_,
    const float* __restrict__ Wd, unsigned short* __restrict__ Td, int Kd, int Nd)
{
    __shared__ float tile[32][33];
    int b = blockIdx.x;
    const float* W; unsigned short* T; int K, Nn;
    const int ta = (Na / 32) * (Ka / 32);
    const int tb = (Nb / 32) * (Kb / 32);
    const int tc = (Nc_ / 32) * (Kc / 32);
    if (b < ta)                { W = Wa; T = Ta; K = Ka; Nn = Na; }
    else if (b < ta + tb)      { b -= ta;           W = Wb; T = Tb; K = Kb; Nn = Nb; }
    else if (b < ta + tb + tc) { b -= ta + tb;      W = Wc; T = Tc; K = Kc; Nn = Nc_; }
    else                       { b -= ta + tb + tc; W = Wd; T = Td; K = Kd; Nn = Nd; }
    const int nx = Nn / 32;
    const int n0 = (b % nx) * 32;
    const int k0 = (b / nx) * 32;
    const int tx = threadIdx.x, ty = threadIdx.y;
#pragma unroll
    for (int i = 0; i < 4; ++i)
        tile[ty + i * 8][tx] = W[(size_t)(k0 + ty + i * 8) * Nn + n0 + tx];
    __syncthreads();
#pragma unroll
    for (int i = 0; i < 4; ++i)
        T[(size_t)(n0 + ty + i * 8) * K + k0 + tx] = f2bf(tile[tx][ty + i * 8]);
}

// ---------------- A-fragment loaders ----------------
__device__ __forceinline__ short8 load_a8(const float* p) {
    float4 f0 = *reinterpret_cast<const float4*>(p);
    float4 f1 = *reinterpret_cast<const float4*>(p + 4);
    short8 v;
    v[0] = (short)f2bf(f0.x); v[1] = (short)f2bf(f0.y);
    v[2] = (short)f2bf(f0.z); v[3] = (short)f2bf(f0.w);
    v[4] = (short)f2bf(f1.x); v[5] = (short)f2bf(f1.y);
    v[6] = (short)f2bf(f1.z); v[7] = (short)f2bf(f1.w);
    return v;
}
__device__ __forceinline__ short8 load_a8(const unsigned short* p) {
    return *reinterpret_cast<const short8*>(p);
}
__device__ __forceinline__ void storeC(float* C, size_t idx, float v)          { C[idx] = v; }
__device__ __forceinline__ void storeC(unsigned short* C, size_t idx, float v) { C[idx] = f2bf(v); }

// ---------------- MFMA GEMM: C[M,Nc] = A[M,K] @ Wt^T(bf16) + bias ----------------
template <typename TA, typename TC, bool RELU>
__global__ __launch_bounds__(256) void mfma_gemm_kernel(
    const TA* __restrict__ A, const unsigned short* __restrict__ Bt,
    const float* __restrict__ bias, TC* __restrict__ C,
    int M, int Nc, int K)
{
    __shared__ unsigned short lds[2 * 128 * 64];

    const int t  = threadIdx.x;
    const int l  = t & 63;
    const int w  = t >> 6;
    const int wm = w >> 1, wn = w & 1;
    const int bm = blockIdx.x * 128;
    const int bn = blockIdx.y * 128;

    f32x4 acc[4][4] = {};

    const int r  = t >> 1;
    const int kh = (t & 1) * 32;

    for (int k0 = 0; k0 < K; k0 += 64) {
        {
            const int gm = bm + r;
            const TA* ap = A + (size_t)gm * K + k0 + kh;
#pragma unroll
            for (int c = 0; c < 4; ++c) {
                short8 v = (gm < M) ? load_a8(ap + c * 8) : (short8)0;
                const int slot = (((t & 1) * 4 + c) ^ (r & 7));
                *reinterpret_cast<short8*>(&lds[r * 64 + slot * 8]) = v;
            }
        }
        {
            const unsigned short* bp = Bt + (size_t)(bn + r) * K + k0 + kh;
#pragma unroll
            for (int c = 0; c < 4; ++c) {
                short8 v = *reinterpret_cast<const short8*>(bp + c * 8);
                const int slot = (((t & 1) * 4 + c) ^ (r & 7));
                *reinterpret_cast<short8*>(&lds[8192 + r * 64 + slot * 8]) = v;
            }
        }
        __syncthreads();

#pragma unroll
        for (int kk = 0; kk < 2; ++kk) {
            short8 af[4], bfr[4];
#pragma unroll
            for (int mf = 0; mf < 4; ++mf) {
                const int row  = wm * 64 + mf * 16 + (l & 15);
                const int slot = (kk * 4 + (l >> 4)) ^ (row & 7);
                af[mf] = *reinterpret_cast<const short8*>(&lds[row * 64 + slot * 8]);
            }
#pragma unroll
            for (int nf = 0; nf < 4; ++nf) {
                const int row  = wn * 64 + nf * 16 + (l & 15);
                const int slot = (kk * 4 + (l >> 4)) ^ (row & 7);
                bfr[nf] = *reinterpret_cast<const short8*>(&lds[8192 + row * 64 + slot * 8]);
            }
#pragma unroll
            for (int mf = 0; mf < 4; ++mf)
#pragma unroll
                for (int nf = 0; nf < 4; ++nf)
                    acc[mf][nf] = __builtin_amdgcn_mfma_f32_16x16x32_bf16(
                        af[mf], bfr[nf], acc[mf][nf], 0, 0, 0);
        }
        __syncthreads();
    }

#pragma unroll
    for (int nf = 0; nf < 4; ++nf) {
        const int n = bn + wn * 64 + nf * 16 + (l & 15);
        const float bv = bias[n];
#pragma unroll
        for (int mf = 0; mf < 4; ++mf) {
#pragma unroll
            for (int rr = 0; rr < 4; ++rr) {
                const int m = bm + wm * 64 + mf * 16 + (l >> 4) * 4 + rr;
                if (m < M) {
                    float v = acc[mf][nf][rr] + bv;
                    if (RELU) v = fmaxf(v, 0.f);
                    storeC(C, (size_t)m * Nc + n, v);
                }
            }
        }
    }
}

// ---------------- CSR build ----------------
__global__ void hist_kernel(const int* __restrict__ dst, int* __restrict__ counts, int E)
{
    int e = blockIdx.x * TPB + threadIdx.x;
    if (e < E) atomicAdd(&counts[dst[e]], 1);
}

__global__ void scan1_kernel(const int* __restrict__ counts,
                             int* __restrict__ local, int* __restrict__ bsum, int N)
{
    __shared__ int sh[TPB];
    const int t = threadIdx.x;
    const int base = blockIdx.x * 1024 + t * 4;
    int v[4];
#pragma unroll
    for (int i = 0; i < 4; ++i) v[i] = (base + i < N) ? counts[base + i] : 0;
    const int s = v[0] + v[1] + v[2] + v[3];
    sh[t] = s;
    __syncthreads();
    for (int d = 1; d < TPB; d <<= 1) {
        int x = (t >= d) ? sh[t - d] : 0;
        __syncthreads();
        sh[t] += x;
        __syncthreads();
    }
    int run = sh[t] - s;
#pragma unroll
    for (int i = 0; i < 4; ++i) {
        if (base + i < N) local[base + i] = run;
        run += v[i];
    }
    if (t == TPB - 1) bsum[blockIdx.x] = sh[TPB - 1];
}

__global__ void scan2_kernel(int* __restrict__ bsum, int nb)
{
    __shared__ int sh[TPB];
    const int t = threadIdx.x;
    const int v = (t < nb) ? bsum[t] : 0;
    sh[t] = v;
    __syncthreads();
    for (int d = 1; d < TPB; d <<= 1) {
        int x = (t >= d) ? sh[t - d] : 0;
        __syncthreads();
        sh[t] += x;
        __syncthreads();
    }
    if (t < nb) bsum[t] = sh[t] - v;
}

__global__ void scan3_kernel(int* __restrict__ offsets, int* __restrict__ cursor,
                             const int* __restrict__ bsum, int N)
{
    const int i = blockIdx.x * TPB + threadIdx.x;
    if (i < N) {
        const int o = offsets[i] + bsum[i >> 10];
        offsets[i] = o;
        cursor[i]  = o;
    }
}

__global__ void build_perm_kernel(const int* __restrict__ src, const int* __restrict__ dst,
                                  int* __restrict__ cursor, int* __restrict__ perm, int E)
{
    int e = blockIdx.x * TPB + threadIdx.x;
    if (e < E) {
        int pos = atomicAdd(&cursor[dst[e]], 1);
        perm[pos] = src[e];
    }
}

// ---------------- CSR gather aggregation (bf16, chunked, shfl-broadcast) ----------------
// F bf16 features/node; CH column chunks (chunk = blockIdx % CH rides XCD round-robin).
// L = lanes per node-chunk, each lane owns one uint2 (4 bf16).
template <int F, int CH, bool WRITE_ZF32>
__global__ __launch_bounds__(256) void agg_kernel(
    const uint2* __restrict__ xt,
    const int* __restrict__ offsets, const int* __restrict__ counts,
    const int* __restrict__ perm,
    uint2* __restrict__ out, float* __restrict__ zf32, int N)
{
    constexpr int RU  = F / 4;        // uint2 per row
    constexpr int L   = RU / CH;      // lanes per node-chunk
    constexpr int NPB = TPB / L;      // nodes per block

    const int chunk = blockIdx.x % CH;
    const int node  = (blockIdx.x / CH) * NPB + threadIdx.x / L;
    const int g     = threadIdx.x % L;
    if (node >= N) return;
    const int col = chunk * L + g;

    const int start = offsets[node];
    const int deg   = counts[node];

    float a0 = 0.f, a1 = 0.f, a2 = 0.f, a3 = 0.f;

    for (int base = 0; base < deg; base += L) {
        const int m = min(L, deg - base);
        const int pidx = perm[start + base + ((g < m) ? g : (m - 1))];
        int j = 0;
        for (; j + 4 <= m; j += 4) {
            const int s0 = __shfl(pidx, j + 0, L);
            const int s1 = __shfl(pidx, j + 1, L);
            const int s2 = __shfl(pidx, j + 2, L);
            const int s3 = __shfl(pidx, j + 3, L);
            const uint2 v0 = xt[(size_t)s0 * RU + col];
            const uint2 v1 = xt[(size_t)s1 * RU + col];
            const uint2 v2 = xt[(size_t)s2 * RU + col];
            const uint2 v3 = xt[(size_t)s3 * RU + col];
            a0 += bflo(v0.x) + bflo(v1.x) + bflo(v2.x) + bflo(v3.x);
            a1 += bfhi(v0.x) + bfhi(v1.x) + bfhi(v2.x) + bfhi(v3.x);
            a2 += bflo(v0.y) + bflo(v1.y) + bflo(v2.y) + bflo(v3.y);
            a3 += bfhi(v0.y) + bfhi(v1.y) + bfhi(v2.y) + bfhi(v3.y);
        }
        for (; j < m; ++j) {
            const int s = __shfl(pidx, j, L);
            const uint2 v = xt[(size_t)s * RU + col];
            a0 += bflo(v.x); a1 += bfhi(v.x);
            a2 += bflo(v.y); a3 += bfhi(v.y);
        }
    }

    const float c = (float)max(deg, 1);
    const uint2 xv = xt[(size_t)node * RU + col];
    const float r0 = fmaxf(a0 / c, 0.f) + bflo(xv.x);
    const float r1 = fmaxf(a1 / c, 0.f) + bfhi(xv.x);
    const float r2 = fmaxf(a2 / c, 0.f) + bflo(xv.y);
    const float r3 = fmaxf(a3 / c, 0.f) + bfhi(xv.y);

    uint2 o;
    o.x = (unsigned int)f2bf(r0) | ((unsigned int)f2bf(r1) << 16);
    o.y = (unsigned int)f2bf(r2) | ((unsigned int)f2bf(r3) << 16);
    out[(size_t)node * RU + col] = o;
    if (WRITE_ZF32) {
        float4 z4 = make_float4(r0, r1, r2, r3);
        *reinterpret_cast<float4*>(&zf32[(size_t)node * F + 4 * col]) = z4;
    }
}

extern "C" void kernel_launch(void* const* d_in, const int* in_sizes, int n_in,
                              void* d_out, int out_size, void* d_ws, size_t ws_size,
                              hipStream_t stream)
{
    const int IN_DIM = 256, HID = 256, LAT = 128, DEC_HID = 512;
    const int N = in_sizes[0] / IN_DIM;     // 50000
    const int E = in_sizes[1] / 2;          // 800000

    const float* x   = (const float*)d_in[0];
    const int*   ei  = (const int*)d_in[1];
    const float* W1  = (const float*)d_in[2];
    const float* b1  = (const float*)d_in[3];
    const float* W2  = (const float*)d_in[4];
    const float* b2  = (const float*)d_in[5];
    const float* Wd1 = (const float*)d_in[6];
    const float* bd1 = (const float*)d_in[7];
    const float* Wd2 = (const float*)d_in[8];
    const float* bd2 = (const float*)d_in[9];

    const int* src = ei;
    const int* dst = ei + E;

    unsigned short* xt1  = (unsigned short*)d_ws;             // [N][256]
    unsigned short* h    = xt1  + (size_t)N * 256;            // [N][256]
    unsigned short* xt2  = h    + (size_t)N * 256;            // [N][128]
    unsigned short* zbf  = xt2  + (size_t)N * 128;            // [N][128]
    unsigned short* hdec = zbf  + (size_t)N * 128;            // [N][512]
    unsigned short* wt1  = hdec + (size_t)N * 512;            // [256][256]
    unsigned short* wt2  = wt1  + 256 * 256;                  // [128][256]
    unsigned short* wtd1 = wt2  + 128 * 256;                  // [512][128]
    unsigned short* wtd2 = wtd1 + 512 * 128;                  // [256][512]
    int* counts  = (int*)(wtd2 + 256 * 512);
    int* offsets = counts + N;
    int* cursor  = offsets + N;
    int* bsum    = cursor + N;
    int* perm    = bsum + 256;

    float* out_xhat = (float*)d_out;
    float* out_z    = out_xhat + (size_t)N * IN_DIM;

    dim3 blk(TPB);
    const int egrid = (E + TPB - 1) / TPB;
    const int mblocks = (N + 127) / 128;
    const int nscan = (N + 1023) / 1024;

    // ---- fused weight transpose/convert ----
    {
        const int tiles = (HID/32)*(IN_DIM/32) + (LAT/32)*(HID/32)
                        + (DEC_HID/32)*(LAT/32) + (IN_DIM/32)*(DEC_HID/32);
        transpose_convert_all<<<tiles, dim3(32, 8), 0, stream>>>(
            W1, wt1, IN_DIM, HID,  W2, wt2, HID, LAT,
            Wd1, wtd1, LAT, DEC_HID,  Wd2, wtd2, DEC_HID, IN_DIM);
    }

    // ---- CSR build ----
    hipMemsetAsync(counts, 0, (size_t)N * 4, stream);
    hist_kernel<<<egrid, blk, 0, stream>>>(dst, counts, E);
    scan1_kernel<<<nscan, blk, 0, stream>>>(counts, offsets, bsum, N);
    scan2_kernel<<<1, blk, 0, stream>>>(bsum, nscan);
    scan3_kernel<<<(N + TPB - 1) / TPB, blk, 0, stream>>>(offsets, cursor, bsum, N);
    build_perm_kernel<<<egrid, blk, 0, stream>>>(src, dst, cursor, perm, E);

    // ---- GCN layer 1 ----
    mfma_gemm_kernel<float, unsigned short, false><<<dim3(mblocks, HID / 128), blk, 0, stream>>>(
        x, wt1, b1, xt1, N, HID, IN_DIM);
    {   // F=256, CH=4 (16 lanes/node, 16 nodes/block)
        const int ngroups = (N + 15) / 16;
        agg_kernel<256, 4, false><<<ngroups * 4, blk, 0, stream>>>(
            (const uint2*)xt1, offsets, counts, perm, (uint2*)h, nullptr, N);
    }

    // ---- GCN layer 2 ----
    mfma_gemm_kernel<unsigned short, unsigned short, false><<<dim3(mblocks, LAT / 128), blk, 0, stream>>>(
        h, wt2, b2, xt2, N, LAT, HID);
    {   // F=128, CH=1 (32 lanes/node, 8 nodes/block)
        const int ngroups = (N + 7) / 8;
        agg_kernel<128, 1, true><<<ngroups, blk, 0, stream>>>(
            (const uint2*)xt2, offsets, counts, perm, (uint2*)zbf, out_z, N);
    }

    // ---- decoder ----
    mfma_gemm_kernel<unsigned short, unsigned short, true><<<dim3(mblocks, DEC_HID / 128), blk, 0, stream>>>(
        zbf, wtd1, bd1, hdec, N, DEC_HID, LAT);
    mfma_gemm_kernel<unsigned short, float, false><<<dim3(mblocks, IN_DIM / 128), blk, 0, stream>>>(
        hdec, wtd2, bd2, out_xhat, N, IN_DIM, DEC_HID);
}

// Round 8
// 288.499 us; speedup vs baseline: 5.3855x; 1.1940x over previous
//
#include <hip/hip_runtime.h>
#include <hip/hip_bf16.h>

#define TPB 256

typedef __attribute__((ext_vector_type(8))) short short8;
typedef __attribute__((ext_vector_type(4))) float f32x4;

__device__ __forceinline__ unsigned short f2bf(float f) {
    unsigned int u = __float_as_uint(f);
    u = (u + 0x7FFFu + ((u >> 16) & 1u)) >> 16;   // RNE
    return (unsigned short)u;
}
__device__ __forceinline__ float bflo(unsigned int u) { return __uint_as_float(u << 16); }
__device__ __forceinline__ float bfhi(unsigned int u) { return __uint_as_float(u & 0xFFFF0000u); }

// ---------------- fused weight transpose + f32->bf16 for all 4 weights ----------------
__global__ void transpose_convert_all(
    const float* __restrict__ Wa, unsigned short* __restrict__ Ta, int Ka, int Na,
    const float* __restrict__ Wb, unsigned short* __restrict__ Tb, int Kb, int Nb,
    const float* __restrict__ Wc, unsigned short* __restrict__ Tc, int Kc, int Nc_,
    const float* __restrict__ Wd, unsigned short* __restrict__ Td, int Kd, int Nd)
{
    __shared__ float tile[32][33];
    int b = blockIdx.x;
    const float* W; unsigned short* T; int K, Nn;
    const int ta = (Na / 32) * (Ka / 32);
    const int tb = (Nb / 32) * (Kb / 32);
    const int tc = (Nc_ / 32) * (Kc / 32);
    if (b < ta)                { W = Wa; T = Ta; K = Ka; Nn = Na; }
    else if (b < ta + tb)      { b -= ta;           W = Wb; T = Tb; K = Kb; Nn = Nb; }
    else if (b < ta + tb + tc) { b -= ta + tb;      W = Wc; T = Tc; K = Kc; Nn = Nc_; }
    else                       { b -= ta + tb + tc; W = Wd; T = Td; K = Kd; Nn = Nd; }
    const int nx = Nn / 32;
    const int n0 = (b % nx) * 32;
    const int k0 = (b / nx) * 32;
    const int tx = threadIdx.x, ty = threadIdx.y;
#pragma unroll
    for (int i = 0; i < 4; ++i)
        tile[ty + i * 8][tx] = W[(size_t)(k0 + ty + i * 8) * Nn + n0 + tx];
    __syncthreads();
#pragma unroll
    for (int i = 0; i < 4; ++i)
        T[(size_t)(n0 + ty + i * 8) * K + k0 + tx] = f2bf(tile[tx][ty + i * 8]);
}

// ---------------- A-prefetch register blocks ----------------
struct ARegsBF {
    short8 v[2];
    __device__ __forceinline__ void load(const unsigned short* A, int K, int bm,
                                         int sr, int c8, int k0, int M) {
#pragma unroll
        for (int i = 0; i < 2; ++i) {
            const int gm = bm + sr + i * 32;
            v[i] = (gm < M) ? *reinterpret_cast<const short8*>(A + (size_t)gm * K + k0 + c8 * 8)
                            : (short8)0;
        }
    }
    __device__ __forceinline__ short8 get(int i) const { return v[i]; }
};
struct ARegsF32 {
    float4 v[2][2];
    __device__ __forceinline__ void load(const float* A, int K, int bm,
                                         int sr, int c8, int k0, int M) {
#pragma unroll
        for (int i = 0; i < 2; ++i) {
            const int gm = bm + sr + i * 32;
            if (gm < M) {
                const float* p = A + (size_t)gm * K + k0 + c8 * 8;
                v[i][0] = *reinterpret_cast<const float4*>(p);
                v[i][1] = *reinterpret_cast<const float4*>(p + 4);
            } else {
                v[i][0] = make_float4(0.f, 0.f, 0.f, 0.f);
                v[i][1] = make_float4(0.f, 0.f, 0.f, 0.f);
            }
        }
    }
    __device__ __forceinline__ short8 get(int i) const {
        short8 r;
        r[0] = (short)f2bf(v[i][0].x); r[1] = (short)f2bf(v[i][0].y);
        r[2] = (short)f2bf(v[i][0].z); r[3] = (short)f2bf(v[i][0].w);
        r[4] = (short)f2bf(v[i][1].x); r[5] = (short)f2bf(v[i][1].y);
        r[6] = (short)f2bf(v[i][1].z); r[7] = (short)f2bf(v[i][1].w);
        return r;
    }
};
template <typename TA> struct ASel;
template <> struct ASel<float>          { using type = ARegsF32; };
template <> struct ASel<unsigned short> { using type = ARegsBF;  };

// ---------------- coalesced epilogue copy-out ----------------
__device__ __forceinline__ void copy_out(unsigned short* C, const float* Cst, const float* bias,
                                         int bm, int bn, int M, int Nc, int t, bool doRelu) {
#pragma unroll
    for (int it = 0; it < 4; ++it) {
        const int idx = it * 2048 + t * 8;
        const int row = idx >> 7, col = idx & 127;
        const int m = bm + row;
        if (m >= M) continue;
        float4 v0 = *reinterpret_cast<const float4*>(&Cst[idx]);
        float4 v1 = *reinterpret_cast<const float4*>(&Cst[idx + 4]);
        float4 b0 = *reinterpret_cast<const float4*>(&bias[bn + col]);
        float4 b1 = *reinterpret_cast<const float4*>(&bias[bn + col + 4]);
        float o[8] = {v0.x + b0.x, v0.y + b0.y, v0.z + b0.z, v0.w + b0.w,
                      v1.x + b1.x, v1.y + b1.y, v1.z + b1.z, v1.w + b1.w};
        short8 s;
#pragma unroll
        for (int j = 0; j < 8; ++j) {
            const float vv = doRelu ? fmaxf(o[j], 0.f) : o[j];
            s[j] = (short)f2bf(vv);
        }
        *reinterpret_cast<short8*>(&C[(size_t)m * Nc + bn + col]) = s;
    }
}
__device__ __forceinline__ void copy_out(float* C, const float* Cst, const float* bias,
                                         int bm, int bn, int M, int Nc, int t, bool doRelu) {
#pragma unroll
    for (int it = 0; it < 8; ++it) {
        const int idx = it * 1024 + t * 4;
        const int row = idx >> 7, col = idx & 127;
        const int m = bm + row;
        if (m >= M) continue;
        float4 v = *reinterpret_cast<const float4*>(&Cst[idx]);
        float4 b = *reinterpret_cast<const float4*>(&bias[bn + col]);
        v.x += b.x; v.y += b.y; v.z += b.z; v.w += b.w;
        if (doRelu) {
            v.x = fmaxf(v.x, 0.f); v.y = fmaxf(v.y, 0.f);
            v.z = fmaxf(v.z, 0.f); v.w = fmaxf(v.w, 0.f);
        }
        *reinterpret_cast<float4*>(&C[(size_t)m * Nc + bn + col]) = v;
    }
}

// ---------------- MFMA GEMM: C[M,Nc] = A[M,K] @ Wt^T(bf16) + bias ----------------
// 64x128 tile, BK=64, 4 waves (2x2, wave-tile 32x64), reg-prefetch dbuf, LDS epilogue.
template <typename TA, typename TC, bool RELU>
__global__ __launch_bounds__(256) void mfma_gemm_kernel(
    const TA* __restrict__ A, const unsigned short* __restrict__ Bt,
    const float* __restrict__ bias, TC* __restrict__ C,
    int M, int Nc, int K)
{
    __shared__ unsigned short lds_s[16384];   // 32KB: A[64][64]@0, B[128][64]@4096; epilogue f32 [64][128]

    const int t  = threadIdx.x;
    const int l  = t & 63;
    const int w  = t >> 6;
    const int wm = w >> 1, wn = w & 1;    // wave tile 32x64
    const int bm = blockIdx.x * 64;
    const int bn = blockIdx.y * 128;

    const int sr = t >> 3;     // staging row 0..31
    const int c8 = t & 7;      // 16B chunk within 64-elem row

    f32x4 acc[2][4] = {};

    typename ASel<TA>::type ar;
    short8 br[4];

    auto loadB = [&](int k0) {
#pragma unroll
        for (int i = 0; i < 4; ++i) {
            const int rb = sr + i * 32;
            br[i] = *reinterpret_cast<const short8*>(Bt + (size_t)(bn + rb) * K + k0 + c8 * 8);
        }
    };
    auto writeTiles = [&]() {
#pragma unroll
        for (int i = 0; i < 2; ++i) {
            const int r = sr + i * 32;
            const int slot = c8 ^ (r & 7);
            *reinterpret_cast<short8*>(&lds_s[r * 64 + slot * 8]) = ar.get(i);
        }
#pragma unroll
        for (int i = 0; i < 4; ++i) {
            const int r = sr + i * 32;
            const int slot = c8 ^ (r & 7);
            *reinterpret_cast<short8*>(&lds_s[4096 + r * 64 + slot * 8]) = br[i];
        }
    };

    // prologue: stage tile 0
    ar.load(A, K, bm, sr, c8, 0, M);
    loadB(0);
    writeTiles();
    __syncthreads();

    for (int k0 = 0; k0 < K; k0 += 64) {
        const bool nxt = (k0 + 64) < K;
        if (nxt) {                       // issue next-tile loads; results used after barrier
            ar.load(A, K, bm, sr, c8, k0 + 64, M);
            loadB(k0 + 64);
        }

#pragma unroll
        for (int kk = 0; kk < 2; ++kk) {
            short8 af[2], bf4[4];
#pragma unroll
            for (int mf = 0; mf < 2; ++mf) {
                const int row  = wm * 32 + mf * 16 + (l & 15);
                const int slot = (kk * 4 + (l >> 4)) ^ (row & 7);
                af[mf] = *reinterpret_cast<const short8*>(&lds_s[row * 64 + slot * 8]);
            }
#pragma unroll
            for (int nf = 0; nf < 4; ++nf) {
                const int row  = wn * 64 + nf * 16 + (l & 15);
                const int slot = (kk * 4 + (l >> 4)) ^ (row & 7);
                bf4[nf] = *reinterpret_cast<const short8*>(&lds_s[4096 + row * 64 + slot * 8]);
            }
#pragma unroll
            for (int mf = 0; mf < 2; ++mf)
#pragma unroll
                for (int nf = 0; nf < 4; ++nf)
                    acc[mf][nf] = __builtin_amdgcn_mfma_f32_16x16x32_bf16(
                        af[mf], bf4[nf], acc[mf][nf], 0, 0, 0);
        }
        __syncthreads();
        if (nxt) { writeTiles(); __syncthreads(); }
    }

    // ---- epilogue: stage f32 C tile in LDS, coalesced bias/relu/store ----
    float* Cst = reinterpret_cast<float*>(lds_s);
#pragma unroll
    for (int mf = 0; mf < 2; ++mf)
#pragma unroll
        for (int nf = 0; nf < 4; ++nf)
#pragma unroll
            for (int rr = 0; rr < 4; ++rr) {
                const int row = wm * 32 + mf * 16 + (l >> 4) * 4 + rr;
                const int col = wn * 64 + nf * 16 + (l & 15);
                Cst[row * 128 + col] = acc[mf][nf][rr];
            }
    __syncthreads();
    copy_out(C, Cst, bias, bm, bn, M, Nc, t, RELU);
}

// ---------------- CSR build ----------------
__global__ void hist_kernel(const int* __restrict__ dst, int* __restrict__ counts, int E)
{
    int e = blockIdx.x * TPB + threadIdx.x;
    if (e < E) atomicAdd(&counts[dst[e]], 1);
}

__global__ void scan1_kernel(const int* __restrict__ counts,
                             int* __restrict__ local, int* __restrict__ bsum, int N)
{
    __shared__ int sh[TPB];
    const int t = threadIdx.x;
    const int base = blockIdx.x * 1024 + t * 4;
    int v[4];
#pragma unroll
    for (int i = 0; i < 4; ++i) v[i] = (base + i < N) ? counts[base + i] : 0;
    const int s = v[0] + v[1] + v[2] + v[3];
    sh[t] = s;
    __syncthreads();
    for (int d = 1; d < TPB; d <<= 1) {
        int x = (t >= d) ? sh[t - d] : 0;
        __syncthreads();
        sh[t] += x;
        __syncthreads();
    }
    int run = sh[t] - s;
#pragma unroll
    for (int i = 0; i < 4; ++i) {
        if (base + i < N) local[base + i] = run;
        run += v[i];
    }
    if (t == TPB - 1) bsum[blockIdx.x] = sh[TPB - 1];
}

__global__ void scan2_kernel(int* __restrict__ bsum, int nb)
{
    __shared__ int sh[TPB];
    const int t = threadIdx.x;
    const int v = (t < nb) ? bsum[t] : 0;
    sh[t] = v;
    __syncthreads();
    for (int d = 1; d < TPB; d <<= 1) {
        int x = (t >= d) ? sh[t - d] : 0;
        __syncthreads();
        sh[t] += x;
        __syncthreads();
    }
    if (t < nb) bsum[t] = sh[t] - v;
}

__global__ void scan3_kernel(int* __restrict__ offsets, int* __restrict__ cursor,
                             const int* __restrict__ bsum, int N)
{
    const int i = blockIdx.x * TPB + threadIdx.x;
    if (i < N) {
        const int o = offsets[i] + bsum[i >> 10];
        offsets[i] = o;
        cursor[i]  = o;
    }
}

__global__ void build_perm_kernel(const int* __restrict__ src, const int* __restrict__ dst,
                                  int* __restrict__ cursor, int* __restrict__ perm, int E)
{
    int e = blockIdx.x * TPB + threadIdx.x;
    if (e < E) {
        int pos = atomicAdd(&cursor[dst[e]], 1);
        perm[pos] = src[e];
    }
}

// ---------------- CSR gather aggregation (bf16, chunked, shfl-broadcast) ----------------
template <int F, int CH, bool WRITE_ZF32>
__global__ __launch_bounds__(256) void agg_kernel(
    const uint2* __restrict__ xt,
    const int* __restrict__ offsets, const int* __restrict__ counts,
    const int* __restrict__ perm,
    uint2* __restrict__ out, float* __restrict__ zf32, int N)
{
    constexpr int RU  = F / 4;
    constexpr int L   = RU / CH;
    constexpr int NPB = TPB / L;

    const int chunk = blockIdx.x % CH;
    const int node  = (blockIdx.x / CH) * NPB + threadIdx.x / L;
    const int g     = threadIdx.x % L;
    if (node >= N) return;
    const int col = chunk * L + g;

    const int start = offsets[node];
    const int deg   = counts[node];

    float a0 = 0.f, a1 = 0.f, a2 = 0.f, a3 = 0.f;

    for (int base = 0; base < deg; base += L) {
        const int m = min(L, deg - base);
        const int pidx = perm[start + base + ((g < m) ? g : (m - 1))];
        int j = 0;
        for (; j + 4 <= m; j += 4) {
            const int s0 = __shfl(pidx, j + 0, L);
            const int s1 = __shfl(pidx, j + 1, L);
            const int s2 = __shfl(pidx, j + 2, L);
            const int s3 = __shfl(pidx, j + 3, L);
            const uint2 v0 = xt[(size_t)s0 * RU + col];
            const uint2 v1 = xt[(size_t)s1 * RU + col];
            const uint2 v2 = xt[(size_t)s2 * RU + col];
            const uint2 v3 = xt[(size_t)s3 * RU + col];
            a0 += bflo(v0.x) + bflo(v1.x) + bflo(v2.x) + bflo(v3.x);
            a1 += bfhi(v0.x) + bfhi(v1.x) + bfhi(v2.x) + bfhi(v3.x);
            a2 += bflo(v0.y) + bflo(v1.y) + bflo(v2.y) + bflo(v3.y);
            a3 += bfhi(v0.y) + bfhi(v1.y) + bfhi(v2.y) + bfhi(v3.y);
        }
        for (; j < m; ++j) {
            const int s = __shfl(pidx, j, L);
            const uint2 v = xt[(size_t)s * RU + col];
            a0 += bflo(v.x); a1 += bfhi(v.x);
            a2 += bflo(v.y); a3 += bfhi(v.y);
        }
    }

    const float c = (float)max(deg, 1);
    const uint2 xv = xt[(size_t)node * RU + col];
    const float r0 = fmaxf(a0 / c, 0.f) + bflo(xv.x);
    const float r1 = fmaxf(a1 / c, 0.f) + bfhi(xv.x);
    const float r2 = fmaxf(a2 / c, 0.f) + bflo(xv.y);
    const float r3 = fmaxf(a3 / c, 0.f) + bfhi(xv.y);

    uint2 o;
    o.x = (unsigned int)f2bf(r0) | ((unsigned int)f2bf(r1) << 16);
    o.y = (unsigned int)f2bf(r2) | ((unsigned int)f2bf(r3) << 16);
    out[(size_t)node * RU + col] = o;
    if (WRITE_ZF32) {
        float4 z4 = make_float4(r0, r1, r2, r3);
        *reinterpret_cast<float4*>(&zf32[(size_t)node * F + 4 * col]) = z4;
    }
}

extern "C" void kernel_launch(void* const* d_in, const int* in_sizes, int n_in,
                              void* d_out, int out_size, void* d_ws, size_t ws_size,
                              hipStream_t stream)
{
    const int IN_DIM = 256, HID = 256, LAT = 128, DEC_HID = 512;
    const int N = in_sizes[0] / IN_DIM;     // 50000
    const int E = in_sizes[1] / 2;          // 800000

    const float* x   = (const float*)d_in[0];
    const int*   ei  = (const int*)d_in[1];
    const float* W1  = (const float*)d_in[2];
    const float* b1  = (const float*)d_in[3];
    const float* W2  = (const float*)d_in[4];
    const float* b2  = (const float*)d_in[5];
    const float* Wd1 = (const float*)d_in[6];
    const float* bd1 = (const float*)d_in[7];
    const float* Wd2 = (const float*)d_in[8];
    const float* bd2 = (const float*)d_in[9];

    const int* src = ei;
    const int* dst = ei + E;

    unsigned short* xt1  = (unsigned short*)d_ws;             // [N][256]
    unsigned short* h    = xt1  + (size_t)N * 256;            // [N][256]
    unsigned short* xt2  = h    + (size_t)N * 256;            // [N][128]
    unsigned short* zbf  = xt2  + (size_t)N * 128;            // [N][128]
    unsigned short* hdec = zbf  + (size_t)N * 128;            // [N][512]
    unsigned short* wt1  = hdec + (size_t)N * 512;            // [256][256]
    unsigned short* wt2  = wt1  + 256 * 256;                  // [128][256]
    unsigned short* wtd1 = wt2  + 128 * 256;                  // [512][128]
    unsigned short* wtd2 = wtd1 + 512 * 128;                  // [256][512]
    int* counts  = (int*)(wtd2 + 256 * 512);
    int* offsets = counts + N;
    int* cursor  = offsets + N;
    int* bsum    = cursor + N;
    int* perm    = bsum + 256;

    float* out_xhat = (float*)d_out;
    float* out_z    = out_xhat + (size_t)N * IN_DIM;

    dim3 blk(TPB);
    const int egrid = (E + TPB - 1) / TPB;
    const int mb64 = (N + 63) / 64;
    const int nscan = (N + 1023) / 1024;

    // ---- fused weight transpose/convert ----
    {
        const int tiles = (HID/32)*(IN_DIM/32) + (LAT/32)*(HID/32)
                        + (DEC_HID/32)*(LAT/32) + (IN_DIM/32)*(DEC_HID/32);
        transpose_convert_all<<<tiles, dim3(32, 8), 0, stream>>>(
            W1, wt1, IN_DIM, HID,  W2, wt2, HID, LAT,
            Wd1, wtd1, LAT, DEC_HID,  Wd2, wtd2, DEC_HID, IN_DIM);
    }

    // ---- CSR build ----
    hipMemsetAsync(counts, 0, (size_t)N * 4, stream);
    hist_kernel<<<egrid, blk, 0, stream>>>(dst, counts, E);
    scan1_kernel<<<nscan, blk, 0, stream>>>(counts, offsets, bsum, N);
    scan2_kernel<<<1, blk, 0, stream>>>(bsum, nscan);
    scan3_kernel<<<(N + TPB - 1) / TPB, blk, 0, stream>>>(offsets, cursor, bsum, N);
    build_perm_kernel<<<egrid, blk, 0, stream>>>(src, dst, cursor, perm, E);

    // ---- GCN layer 1 ----
    mfma_gemm_kernel<float, unsigned short, false><<<dim3(mb64, HID / 128), blk, 0, stream>>>(
        x, wt1, b1, xt1, N, HID, IN_DIM);
    {   // F=256, CH=4
        const int ngroups = (N + 15) / 16;
        agg_kernel<256, 4, false><<<ngroups * 4, blk, 0, stream>>>(
            (const uint2*)xt1, offsets, counts, perm, (uint2*)h, nullptr, N);
    }

    // ---- GCN layer 2 ----
    mfma_gemm_kernel<unsigned short, unsigned short, false><<<dim3(mb64, LAT / 128), blk, 0, stream>>>(
        h, wt2, b2, xt2, N, LAT, HID);
    {   // F=128, CH=1
        const int ngroups = (N + 7) / 8;
        agg_kernel<128, 1, true><<<ngroups, blk, 0, stream>>>(
            (const uint2*)xt2, offsets, counts, perm, (uint2*)zbf, out_z, N);
    }

    // ---- decoder ----
    mfma_gemm_kernel<unsigned short, unsigned short, true><<<dim3(mb64, DEC_HID / 128), blk, 0, stream>>>(
        zbf, wtd1, bd1, hdec, N, DEC_HID, LAT);
    mfma_gemm_kernel<unsigned short, float, false><<<dim3(mb64, IN_DIM / 128), blk, 0, stream>>>(
        hdec, wtd2, bd2, out_xhat, N, IN_DIM, DEC_HID);
}